// Round 8
// baseline (121.383 us; speedup 1.0000x reference)
//
#include <hip/hip_runtime.h>

// DifferentiableRankIntegration, B=1024, tau=0.1, K=60.
// u = s/tau. sigma(u_a - u_b) needed for rank sums AN = sum nf*sigma, AP = sum pf*sigma.
// Value-bucket compaction (25 buckets, width W = range/25 >= 3, bucket-local
// normalization en = e^{u - c_bkt} in [e^-W/2, e^W/2] -- no clamps needed):
//  - In-band (buckets i-1..i+1): EXACT weighted quartic rational:
//      sum_i w_i en_i/(en_i + x) = N_w(x)/D(x), D = prod(x+en_i) (Horner, 1 rcp / 4 terms),
//    numerator coeffs via synthetic division of D by (x+en_i).
//  - Out-of-band: sigma tail expansion (err <= e^{-3W} ~ 1.2e-4/term):
//      above: 1 - r + r^2, below: q - q^2; becomes per-bucket geometric
//      prefix/suffix tables (kappa = e^{-W} recurrence), O(1) per b.
// rank_v = (1+AN)*pf_b + (1+AP)*nf_b ; out = 61*(wv/(60+rk_v)+wl/(60+rk_l)).

constexpr int B = 1024;
constexpr int NT = 256;
constexpr int NB = 25;
constexpr int SLOTCAP = 1104;     // 1024 + up to 75 pads (pad-4 per bucket)
constexpr int QCAP = SLOTCAP / 4; // 276
constexpr int DUMP = 1024;
constexpr float L2E = 1.4426950408889634f;

__global__ __launch_bounds__(NT, 2)
void rank_band_kernel(const float* __restrict__ s_v, const float* __restrict__ s_l,
                      const int* __restrict__ pos_m, const int* __restrict__ neg_m,
                      const float* __restrict__ w_v, const float* __restrict__ w_l,
                      float* __restrict__ out) {
    __shared__ __align__(16) float En[2][SLOTCAP];      // bucket-normalized e^{u-c}
    __shared__ __align__(16) float Cq[2][QCAP][12];     // e1..e4, nA3..0, nP3..0
    __shared__ unsigned short Idx[2][SLOTCAP];
    __shared__ unsigned char Flg[2][SLOTCAP];           // cat (0 = dummy/pad)
    __shared__ unsigned char BktQ[2][QCAP];
    __shared__ int segCnt[2][NB][16];
    __shared__ int segStart[2][NB + 1];
    __shared__ float Tab[2][2][5][32];  // [m][cls AN/AP][P1,P2,Q1,Q2,S0][bkt+2]
    __shared__ float Red[4][4];

    const int r = blockIdx.x;
    const int tid = threadIdx.x;
    const int lane = tid & 63;
    const int wvid = tid >> 6;
    const unsigned long long lmask = (1ull << lane) - 1ull;

    for (int s = tid; s < SLOTCAP; s += NT) {
        En[0][s] = 0.f; En[1][s] = 0.f;
        Idx[0][s] = DUMP; Idx[1][s] = DUMP;
        Flg[0][s] = 0; Flg[1][s] = 0;
    }
    for (int s = tid; s < 2 * 2 * 5 * 32; s += NT) ((float*)Tab)[s] = 0.f;
    __syncthreads();

    // ---- Phase 1: read, u, cat, row min/max ----
    float uu[2][4]; int cat[4];
    float mn[2] = {1e30f, 1e30f}, mx[2] = {-1e30f, -1e30f};
#pragma unroll
    for (int i = 0; i < 4; ++i) {
        const int c = tid + i * NT;
        uu[0][i] = s_v[r * B + c] * 10.0f;
        uu[1][i] = s_l[r * B + c] * 10.0f;
        const int pf = pos_m[r * B + c] != 0, nf = neg_m[r * B + c] != 0;
        cat[i] = pf | (nf << 1);
#pragma unroll
        for (int m = 0; m < 2; ++m) {
            mn[m] = fminf(mn[m], uu[m][i]); mx[m] = fmaxf(mx[m], uu[m][i]);
        }
    }
#pragma unroll
    for (int off = 1; off < 64; off <<= 1) {
#pragma unroll
        for (int m = 0; m < 2; ++m) {
            mn[m] = fminf(mn[m], __shfl_xor(mn[m], off));
            mx[m] = fmaxf(mx[m], __shfl_xor(mx[m], off));
        }
    }
    if (lane == 0) { Red[0][wvid]=mn[0]; Red[1][wvid]=mx[0]; Red[2][wvid]=mn[1]; Red[3][wvid]=mx[1]; }
    __syncthreads();

    float umin[2], Wb[2], invW[2], kap1[2], kap2[2], eW[2];
#pragma unroll
    for (int m = 0; m < 2; ++m) {
        const float lo = fminf(fminf(Red[2*m][0], Red[2*m][1]), fminf(Red[2*m][2], Red[2*m][3]));
        const float hi = fmaxf(fmaxf(Red[2*m+1][0], Red[2*m+1][1]), fmaxf(Red[2*m+1][2], Red[2*m+1][3]));
        umin[m] = lo;
        Wb[m] = fmaxf((hi - lo) * (1.0001f / NB), 3.0f);
        invW[m] = 1.0f / Wb[m];
        kap1[m] = exp2f(-Wb[m] * L2E);
        kap2[m] = kap1[m] * kap1[m];
        eW[m]   = exp2f(Wb[m] * L2E);
    }

    // ---- Phase 1b: bucket keys + deterministic ballot counts ----
    int key[2][4], rk[2][4];
#pragma unroll
    for (int i = 0; i < 4; ++i) {
#pragma unroll
        for (int m = 0; m < 2; ++m) {
            int b = (int)((uu[m][i] - umin[m]) * invW[m]);
            b = b > NB - 1 ? NB - 1 : b;
            key[m][i] = cat[i] ? b : -1;
            rk[m][i] = 0;
        }
        for (int k = 0; k < NB; ++k) {
            unsigned long long b1 = __ballot(key[0][i] == k);
            if (key[0][i] == k) rk[0][i] = (int)__popcll(b1 & lmask);
            if (lane == 0) segCnt[0][k][i * 4 + wvid] = (int)__popcll(b1);
            unsigned long long b2 = __ballot(key[1][i] == k);
            if (key[1][i] == k) rk[1][i] = (int)__popcll(b2 & lmask);
            if (lane == 0) segCnt[1][k][i * 4 + wvid] = (int)__popcll(b2);
        }
    }
    __syncthreads();

    // ---- Phase 2a: padded segment lengths, then prefix ----
    if (tid < 2 * NB) {
        const int m = tid / NB, k = tid % NB;
        int t = 0;
#pragma unroll
        for (int u = 0; u < 16; ++u) t += segCnt[m][k][u];
        segStart[m][k] = (t + 3) & ~3;    // padded length (temp)
    }
    __syncthreads();
    if (tid < 2) {
        int run = 0;
        for (int k = 0; k < NB; ++k) { int t = segStart[tid][k]; segStart[tid][k] = run; run += t; }
        segStart[tid][NB] = run;
    }
    __syncthreads();

    // ---- Phase 2b: placement (bucket-local normalized E) ----
#pragma unroll
    for (int i = 0; i < 4; ++i) {
        if (cat[i]) {
            const int unit = i * 4 + wvid;
#pragma unroll
            for (int m = 0; m < 2; ++m) {
                const int k = key[m][i];
                int pre = 0;
                for (int u = 0; u < unit; ++u) pre += segCnt[m][k][u];
                const int slot = segStart[m][k] + pre + rk[m][i];
                const float cb = umin[m] + ((float)k + 0.5f) * Wb[m];
                En[m][slot] = exp2f((uu[m][i] - cb) * L2E);
                Idx[m][slot] = (unsigned short)(tid + i * NT);
                Flg[m][slot] = (unsigned char)cat[i];
            }
        }
    }
    __syncthreads();

    // ---- Phase 3a: quad coefficients (weighted quartic via synthetic division) ----
#pragma unroll
    for (int m = 0; m < 2; ++m) {
        const int nQ = segStart[m][NB] >> 2;
        for (int q = tid; q < nQ; q += NT) {
            int bq = 0;
            for (int k = 1; k < NB; ++k) bq += (4 * q >= segStart[m][k]);
            BktQ[m][q] = (unsigned char)bq;
            const float4 e4v = *(const float4*)&En[m][4 * q];
            const uchar4 f4 = *(const uchar4*)&Flg[m][4 * q];
            const float en[4] = {e4v.x, e4v.y, e4v.z, e4v.w};
            const int fl[4] = {f4.x, f4.y, f4.z, f4.w};
            const float s01 = en[0] + en[1], p01 = en[0] * en[1];
            const float s23 = en[2] + en[3], p23 = en[2] * en[3];
            const float e1 = s01 + s23;
            const float e2 = fmaf(s01, s23, p01 + p23);
            const float e3 = fmaf(s01, p23, s23 * p01);
            const float e4 = p01 * p23;
            float nA3 = 0.f, nA2 = 0.f, nA1 = 0.f, nA0 = 0.f;
            float nP3 = 0.f, nP2 = 0.f, nP1 = 0.f, nP0 = 0.f;
#pragma unroll
            for (int j = 0; j < 4; ++j) {
                const float b1 = e1 - en[j];
                const float b2 = fmaf(-en[j], b1, e2);
                const float b3 = fmaf(-en[j], b2, e3);
                const float nn = (float)(fl[j] >> 1) * en[j];
                const float pp = (float)(fl[j] & 1) * en[j];
                nA3 += nn; nA2 = fmaf(nn, b1, nA2); nA1 = fmaf(nn, b2, nA1); nA0 = fmaf(nn, b3, nA0);
                nP3 += pp; nP2 = fmaf(pp, b1, nP2); nP1 = fmaf(pp, b2, nP1); nP0 = fmaf(pp, b3, nP0);
            }
            float* row = &Cq[m][q][0];
            row[0] = e1; row[1] = e2; row[2] = e3; row[3] = e4;
            row[4] = nA3; row[5] = nA2; row[6] = nA1; row[7] = nA0;
            row[8] = nP3; row[9] = nP2; row[10] = nP1; row[11] = nP0;
        }
    }
    // ---- Phase 3b: per-bucket tail sums (G1,G2 / H1,H2 / S0 per class) ----
    if (tid < 2 * NB) {
        const int m = tid / NB, k = tid % NB;
        float g1a=0,g2a=0,h1a=0,h2a=0,s0a=0, g1p=0,g2p=0,h1p=0,h2p=0,s0p=0;
        for (int s = segStart[m][k]; s < segStart[m][k + 1]; ++s) {
            const int f = Flg[m][s];
            if (!f) continue;
            const float en = En[m][s];
            const float ren = __builtin_amdgcn_rcpf(en);
            const float nf = (float)(f >> 1), pf = (float)(f & 1);
            g1a = fmaf(nf, en, g1a);  g2a = fmaf(nf, en * en, g2a);
            h1a = fmaf(nf, ren, h1a); h2a = fmaf(nf, ren * ren, h2a); s0a += nf;
            g1p = fmaf(pf, en, g1p);  g2p = fmaf(pf, en * en, g2p);
            h1p = fmaf(pf, ren, h1p); h2p = fmaf(pf, ren * ren, h2p); s0p += pf;
        }
        Tab[m][0][0][k+2]=g1a; Tab[m][0][1][k+2]=g2a; Tab[m][0][2][k+2]=h1a; Tab[m][0][3][k+2]=h2a; Tab[m][0][4][k+2]=s0a;
        Tab[m][1][0][k+2]=g1p; Tab[m][1][1][k+2]=g2p; Tab[m][1][2][k+2]=h1p; Tab[m][1][3][k+2]=h2p; Tab[m][1][4][k+2]=s0p;
    }
    __syncthreads();
    // ---- Phase 3c: geometric prefix (below) / suffix (above) scans ----
    if (tid < 4) {
        const int m = tid >> 1, cls = tid & 1;
        const float k1 = kap1[m], k2 = kap2[m];
        float r1 = 0.f, r2 = 0.f;
        for (int k = 0; k < NB; ++k) {
            r1 = fmaf(r1, k1, Tab[m][cls][0][k+2]); Tab[m][cls][0][k+2] = r1;
            r2 = fmaf(r2, k2, Tab[m][cls][1][k+2]); Tab[m][cls][1][k+2] = r2;
        }
        float q1 = 0.f, q2 = 0.f, s0 = 0.f;
        for (int k = NB - 1; k >= 0; --k) {
            q1 = fmaf(q1, k1, Tab[m][cls][2][k+2]); Tab[m][cls][2][k+2] = q1;
            q2 = fmaf(q2, k2, Tab[m][cls][3][k+2]); Tab[m][cls][3][k+2] = q2;
            s0 += Tab[m][cls][4][k+2];              Tab[m][cls][4][k+2] = s0;
        }
    }
    __syncthreads();

    // ---- Phase 4: main — in-band quartic + out-of-band tails ----
    float AN[2][4] = {{0,0,0,0},{0,0,0,0}}, AP[2][4] = {{0,0,0,0},{0,0,0,0}};
    const int s0i = 4 * tid;
#pragma unroll
    for (int m = 0; m < 2; ++m) {
        const int nS = segStart[m][NB];
        if (s0i < nS) {
            const float4 x4 = *(const float4*)&En[m][s0i];
            const float xb[4] = {x4.x, x4.y, x4.z, x4.w};
            const int ib = BktQ[m][tid];
            const int lo = ib > 0 ? ib - 1 : 0;
            const int hi = ib < NB - 1 ? ib + 1 : NB - 1;
            const int qs = segStart[m][lo] >> 2;
            const int qe = segStart[m][hi + 1] >> 2;
            const float eWm = eW[m], k1m = kap1[m];
            for (int q = qs; q < qe; ++q) {
                const float4 cA = *(const float4*)&Cq[m][q][0];
                const float4 cB = *(const float4*)&Cq[m][q][4];
                const float4 cC = *(const float4*)&Cq[m][q][8];
                const int dq = (int)BktQ[m][q] - ib;
                const float fc = dq < 0 ? eWm : (dq > 0 ? k1m : 1.0f);  // 2 selects, no scratch
#pragma unroll
                for (int i = 0; i < 4; ++i) {
                    const float xs = xb[i] * fc;
                    float t = xs + cA.x;
                    t = fmaf(t, xs, cA.y); t = fmaf(t, xs, cA.z);
                    const float D = fmaf(t, xs, cA.w);
                    float u = fmaf(cB.x, xs, cB.y); u = fmaf(u, xs, cB.z);
                    const float NA = fmaf(u, xs, cB.w);
                    float v = fmaf(cC.x, xs, cC.y); v = fmaf(v, xs, cC.z);
                    const float NP = fmaf(v, xs, cC.w);
                    const float rd = __builtin_amdgcn_rcpf(D);
                    AN[m][i] = fmaf(NA, rd, AN[m][i]);
                    AP[m][i] = fmaf(NP, rd, AP[m][i]);
                }
            }
            // out-of-band tails
#pragma unroll
            for (int i = 0; i < 4; ++i) {
                const float eb = xb[i];
                const float rb = __builtin_amdgcn_rcpf(eb);
                const float tq = rb * kap2[m], sq = eb * kap2[m];
                const float tq2 = tq * tq, sq2 = sq * sq;
                AN[m][i] += tq * Tab[m][0][0][ib] - tq2 * Tab[m][0][1][ib]
                          + Tab[m][0][4][ib+4] - sq * Tab[m][0][2][ib+4] + sq2 * Tab[m][0][3][ib+4];
                AP[m][i] += tq * Tab[m][1][0][ib] - tq2 * Tab[m][1][1][ib]
                          + Tab[m][1][4][ib+4] - sq * Tab[m][1][2][ib+4] + sq2 * Tab[m][1][3][ib+4];
            }
        }
    }
    __syncthreads();   // Cq dead -> overlay A

    // ---- Phase 5: unscatter to original columns (A overlays Cq) ----
    float* A0 = &Cq[0][0][0];
    float* A1 = A0 + 1025;
    float* A2 = A1 + 1025;
    float* A3 = A2 + 1025;
#pragma unroll
    for (int i = 0; i < 4; ++i) {
        const int oiV = Idx[0][s0i + i];
        const int oiL = Idx[1][s0i + i];
        A0[oiV] = AN[0][i]; A1[oiV] = AP[0][i];
        A2[oiL] = AN[1][i]; A3[oiL] = AP[1][i];
    }
    __syncthreads();

    // ---- Phase 6: epilogue ----
#pragma unroll
    for (int i = 0; i < 4; ++i) {
        const int c = tid + i * NT;
        const bool pf = (cat[i] & 1) != 0;
        const bool nf = (cat[i] & 2) != 0;
        const float rkv = (pf ? 1.f + A0[c] : 0.f) + (nf ? 1.f + A1[c] : 0.f);
        const float rkl = (pf ? 1.f + A2[c] : 0.f) + (nf ? 1.f + A3[c] : 0.f);
        out[r * B + c] = 61.f * (w_v[r * B + c] / (60.f + rkv) +
                                 w_l[r * B + c] / (60.f + rkl));
    }
}

extern "C" void kernel_launch(void* const* d_in, const int* in_sizes, int n_in,
                              void* d_out, int out_size, void* d_ws, size_t ws_size,
                              hipStream_t stream) {
    const float* s_v = (const float*)d_in[0];
    const float* s_l = (const float*)d_in[1];
    const int* pos_mask = (const int*)d_in[2];
    const int* neg_mask = (const int*)d_in[3];
    const float* w_v = (const float*)d_in[4];
    const float* w_l = (const float*)d_in[5];
    float* out = (float*)d_out;

    rank_band_kernel<<<B, NT, 0, stream>>>(s_v, s_l, pos_mask, neg_mask,
                                           w_v, w_l, out);
}

// Round 9
// 96.860 us; speedup vs baseline: 1.2532x; 1.2532x over previous
//
#include <hip/hip_runtime.h>
#include <hip/hip_fp16.h>

// DifferentiableRankIntegration, B=1024, tau=0.1, K=60.
// u = s/tau. sigma(u_a - u_b) for rank sums AN = sum nf*sigma, AP = sum pf*sigma.
// Value-bucket compaction (NB buckets, width W>=3, bucket-local normalization
// en = e^{u-c_bkt}):
//  - In-band (buckets ib-1..ib+1): exact weighted quartic rational
//      sum_i w_i en_i/(en_i + x*fc) = N_w(xs)/D(xs), xs = x*fc,
//    D from elementary symmetric polys, N via synthetic division. 1 rcp/4 terms.
//  - Out-of-band: 2-term sigma tail expansion -> per-bucket geometric
//    prefix/suffix tables (kappa = e^-W recurrence), O(1) per b.
// R9 (same math as R8): fp16-packed quad coeffs (LDS 48.6K->35.3K, 4 blk/CU),
// fc from register compares (no per-q BktQ gather), next-q coeff prefetch.

constexpr int B = 1024;
constexpr int NT = 256;
constexpr int NB = 25;
constexpr int SLOTCAP = 1104;     // 1024 + up to 75 pads (pad-4 per bucket)
constexpr int QCAP = SLOTCAP / 4; // 276
constexpr int DUMP = 1024;
constexpr float L2E = 1.4426950408889634f;

constexpr int EN_BYTES = 2 * SLOTCAP * 4;        // 8832
constexpr int CQ_BYTES = 2 * QCAP * 3 * 8;       // 13248
constexpr int POOL_BYTES = EN_BYTES + CQ_BYTES;  // 22080 (A overlay needs 16400)

__global__ __launch_bounds__(NT, 4)
void rank_band2_kernel(const float* __restrict__ s_v, const float* __restrict__ s_l,
                       const int* __restrict__ pos_m, const int* __restrict__ neg_m,
                       const float* __restrict__ w_v, const float* __restrict__ w_l,
                       float* __restrict__ out) {
    __shared__ __align__(16) char pool[POOL_BYTES];
    __shared__ unsigned short Idx[2][SLOTCAP];
    __shared__ unsigned char Flg[2][SLOTCAP];           // cat (0 = dummy/pad)
    __shared__ unsigned char BktQ[2][QCAP];
    __shared__ int segCnt[2][NB][16];
    __shared__ int segStart[2][NB + 1];
    __shared__ float Tab[2][2][5][32];  // [m][cls AN/AP][P1,P2,Q1,Q2,S0][bkt+2]
    __shared__ float Red[4][4];

    float* EnP = (float*)pool;                       // [2][SLOTCAP]
    uint2* CqW = (uint2*)(pool + EN_BYTES);          // [2][QCAP][3] fp16-packed

    const int r = blockIdx.x;
    const int tid = threadIdx.x;
    const int lane = tid & 63;
    const int wvid = tid >> 6;
    const unsigned long long lmask = (1ull << lane) - 1ull;

    for (int s = tid; s < SLOTCAP; s += NT) {
        EnP[s] = 0.f; EnP[SLOTCAP + s] = 0.f;
        Idx[0][s] = DUMP; Idx[1][s] = DUMP;
        Flg[0][s] = 0; Flg[1][s] = 0;
    }
    for (int s = tid; s < 2 * 2 * 5 * 32; s += NT) ((float*)Tab)[s] = 0.f;
    __syncthreads();

    // ---- Phase 1: read, u, cat, row min/max ----
    float uu[2][4]; int cat[4];
    float mn[2] = {1e30f, 1e30f}, mx[2] = {-1e30f, -1e30f};
#pragma unroll
    for (int i = 0; i < 4; ++i) {
        const int c = tid + i * NT;
        uu[0][i] = s_v[r * B + c] * 10.0f;
        uu[1][i] = s_l[r * B + c] * 10.0f;
        const int pf = pos_m[r * B + c] != 0, nf = neg_m[r * B + c] != 0;
        cat[i] = pf | (nf << 1);
#pragma unroll
        for (int m = 0; m < 2; ++m) {
            mn[m] = fminf(mn[m], uu[m][i]); mx[m] = fmaxf(mx[m], uu[m][i]);
        }
    }
#pragma unroll
    for (int off = 1; off < 64; off <<= 1) {
#pragma unroll
        for (int m = 0; m < 2; ++m) {
            mn[m] = fminf(mn[m], __shfl_xor(mn[m], off));
            mx[m] = fmaxf(mx[m], __shfl_xor(mx[m], off));
        }
    }
    if (lane == 0) { Red[0][wvid]=mn[0]; Red[1][wvid]=mx[0]; Red[2][wvid]=mn[1]; Red[3][wvid]=mx[1]; }
    __syncthreads();

    float umin[2], Wb[2], invW[2], kap1[2], kap2[2], eW[2];
#pragma unroll
    for (int m = 0; m < 2; ++m) {
        const float lo = fminf(fminf(Red[2*m][0], Red[2*m][1]), fminf(Red[2*m][2], Red[2*m][3]));
        const float hi = fmaxf(fmaxf(Red[2*m+1][0], Red[2*m+1][1]), fmaxf(Red[2*m+1][2], Red[2*m+1][3]));
        umin[m] = lo;
        Wb[m] = fmaxf((hi - lo) * (1.0001f / NB), 3.0f);
        invW[m] = 1.0f / Wb[m];
        kap1[m] = exp2f(-Wb[m] * L2E);
        kap2[m] = kap1[m] * kap1[m];
        eW[m]   = exp2f(Wb[m] * L2E);
    }

    // ---- Phase 1b: bucket keys + deterministic ballot counts ----
    int key[2][4], rk[2][4];
#pragma unroll
    for (int i = 0; i < 4; ++i) {
#pragma unroll
        for (int m = 0; m < 2; ++m) {
            int b = (int)((uu[m][i] - umin[m]) * invW[m]);
            b = b > NB - 1 ? NB - 1 : b;
            key[m][i] = cat[i] ? b : -1;
            rk[m][i] = 0;
        }
        for (int k = 0; k < NB; ++k) {
            unsigned long long b1 = __ballot(key[0][i] == k);
            if (key[0][i] == k) rk[0][i] = (int)__popcll(b1 & lmask);
            if (lane == 0) segCnt[0][k][i * 4 + wvid] = (int)__popcll(b1);
            unsigned long long b2 = __ballot(key[1][i] == k);
            if (key[1][i] == k) rk[1][i] = (int)__popcll(b2 & lmask);
            if (lane == 0) segCnt[1][k][i * 4 + wvid] = (int)__popcll(b2);
        }
    }
    __syncthreads();

    // ---- Phase 2a: padded segment lengths, then prefix ----
    if (tid < 2 * NB) {
        const int m = tid / NB, k = tid % NB;
        int t = 0;
#pragma unroll
        for (int u = 0; u < 16; ++u) t += segCnt[m][k][u];
        segStart[m][k] = (t + 3) & ~3;    // padded length (temp)
    }
    __syncthreads();
    if (tid < 2) {
        int run = 0;
        for (int k = 0; k < NB; ++k) { int t = segStart[tid][k]; segStart[tid][k] = run; run += t; }
        segStart[tid][NB] = run;
    }
    __syncthreads();

    // ---- Phase 2b: placement (bucket-local normalized E) ----
#pragma unroll
    for (int i = 0; i < 4; ++i) {
        if (cat[i]) {
            const int unit = i * 4 + wvid;
#pragma unroll
            for (int m = 0; m < 2; ++m) {
                const int k = key[m][i];
                int pre = 0;
                for (int u = 0; u < unit; ++u) pre += segCnt[m][k][u];
                const int slot = segStart[m][k] + pre + rk[m][i];
                const float cb = umin[m] + ((float)k + 0.5f) * Wb[m];
                EnP[m * SLOTCAP + slot] = exp2f((uu[m][i] - cb) * L2E);
                Idx[m][slot] = (unsigned short)(tid + i * NT);
                Flg[m][slot] = (unsigned char)cat[i];
            }
        }
    }
    __syncthreads();

    // ---- Phase 3a: quad coefficients (weighted quartic, fp16-packed) ----
#pragma unroll
    for (int m = 0; m < 2; ++m) {
        const int nQ = segStart[m][NB] >> 2;
        const float* En = EnP + m * SLOTCAP;
        for (int q = tid; q < nQ; q += NT) {
            int bq = 0;
            for (int k = 1; k < NB; ++k) bq += (4 * q >= segStart[m][k]);
            BktQ[m][q] = (unsigned char)bq;
            const float4 e4v = *(const float4*)&En[4 * q];
            const uchar4 f4 = *(const uchar4*)&Flg[m][4 * q];
            const float en[4] = {e4v.x, e4v.y, e4v.z, e4v.w};
            const int fl[4] = {f4.x, f4.y, f4.z, f4.w};
            const float s01 = en[0] + en[1], p01 = en[0] * en[1];
            const float s23 = en[2] + en[3], p23 = en[2] * en[3];
            const float e1 = s01 + s23;
            const float e2 = fmaf(s01, s23, p01 + p23);
            const float e3 = fmaf(s01, p23, s23 * p01);
            const float e4 = p01 * p23;
            float nA3 = 0.f, nA2 = 0.f, nA1 = 0.f, nA0 = 0.f;
            float nP3 = 0.f, nP2 = 0.f, nP1 = 0.f, nP0 = 0.f;
#pragma unroll
            for (int j = 0; j < 4; ++j) {
                const float b1 = e1 - en[j];
                const float b2 = fmaf(-en[j], b1, e2);
                const float b3 = fmaf(-en[j], b2, e3);
                const float nn = (float)(fl[j] >> 1) * en[j];
                const float pp = (float)(fl[j] & 1) * en[j];
                nA3 += nn; nA2 = fmaf(nn, b1, nA2); nA1 = fmaf(nn, b2, nA1); nA0 = fmaf(nn, b3, nA0);
                nP3 += pp; nP2 = fmaf(pp, b1, nP2); nP1 = fmaf(pp, b2, nP1); nP0 = fmaf(pp, b3, nP0);
            }
            __half2 hA = __floats2half2_rn(e1, e2);
            __half2 hB = __floats2half2_rn(e3, e4);
            __half2 hC = __floats2half2_rn(nA3, nA2);
            __half2 hD = __floats2half2_rn(nA1, nA0);
            __half2 hE = __floats2half2_rn(nP3, nP2);
            __half2 hF = __floats2half2_rn(nP1, nP0);
            uint2* dst = CqW + (m * QCAP + q) * 3;
            dst[0] = make_uint2(reinterpret_cast<unsigned&>(hA), reinterpret_cast<unsigned&>(hB));
            dst[1] = make_uint2(reinterpret_cast<unsigned&>(hC), reinterpret_cast<unsigned&>(hD));
            dst[2] = make_uint2(reinterpret_cast<unsigned&>(hE), reinterpret_cast<unsigned&>(hF));
        }
    }
    // ---- Phase 3b: per-bucket tail sums (G1,G2 / H1,H2 / S0 per class) ----
    if (tid < 2 * NB) {
        const int m = tid / NB, k = tid % NB;
        const float* En = EnP + m * SLOTCAP;
        float g1a=0,g2a=0,h1a=0,h2a=0,s0a=0, g1p=0,g2p=0,h1p=0,h2p=0,s0p=0;
        for (int s = segStart[m][k]; s < segStart[m][k + 1]; ++s) {
            const int f = Flg[m][s];
            if (!f) continue;
            const float en = En[s];
            const float ren = __builtin_amdgcn_rcpf(en);
            const float nf = (float)(f >> 1), pf = (float)(f & 1);
            g1a = fmaf(nf, en, g1a);  g2a = fmaf(nf, en * en, g2a);
            h1a = fmaf(nf, ren, h1a); h2a = fmaf(nf, ren * ren, h2a); s0a += nf;
            g1p = fmaf(pf, en, g1p);  g2p = fmaf(pf, en * en, g2p);
            h1p = fmaf(pf, ren, h1p); h2p = fmaf(pf, ren * ren, h2p); s0p += pf;
        }
        Tab[m][0][0][k+2]=g1a; Tab[m][0][1][k+2]=g2a; Tab[m][0][2][k+2]=h1a; Tab[m][0][3][k+2]=h2a; Tab[m][0][4][k+2]=s0a;
        Tab[m][1][0][k+2]=g1p; Tab[m][1][1][k+2]=g2p; Tab[m][1][2][k+2]=h1p; Tab[m][1][3][k+2]=h2p; Tab[m][1][4][k+2]=s0p;
    }
    __syncthreads();
    // ---- Phase 3c: geometric prefix (below) / suffix (above) scans ----
    if (tid < 4) {
        const int m = tid >> 1, cls = tid & 1;
        const float k1 = kap1[m], k2 = kap2[m];
        float r1 = 0.f, r2 = 0.f;
        for (int k = 0; k < NB; ++k) {
            r1 = fmaf(r1, k1, Tab[m][cls][0][k+2]); Tab[m][cls][0][k+2] = r1;
            r2 = fmaf(r2, k2, Tab[m][cls][1][k+2]); Tab[m][cls][1][k+2] = r2;
        }
        float q1 = 0.f, q2 = 0.f, s0 = 0.f;
        for (int k = NB - 1; k >= 0; --k) {
            q1 = fmaf(q1, k1, Tab[m][cls][2][k+2]); Tab[m][cls][2][k+2] = q1;
            q2 = fmaf(q2, k2, Tab[m][cls][3][k+2]); Tab[m][cls][3][k+2] = q2;
            s0 += Tab[m][cls][4][k+2];              Tab[m][cls][4][k+2] = s0;
        }
    }
    __syncthreads();

    // ---- Phase 4: main — in-band quartic + out-of-band tails ----
    float AN[2][4] = {{0,0,0,0},{0,0,0,0}}, AP[2][4] = {{0,0,0,0},{0,0,0,0}};
    const int s0i = 4 * tid;
#pragma unroll
    for (int m = 0; m < 2; ++m) {
        const int nS = segStart[m][NB];
        if (s0i < nS) {
            const float* En = EnP + m * SLOTCAP;
            const float4 x4 = *(const float4*)&En[s0i];
            const float xb[4] = {x4.x, x4.y, x4.z, x4.w};
            const int ib = BktQ[m][tid];
            const int lo = ib > 0 ? ib - 1 : 0;
            const int hi = ib < NB - 1 ? ib + 1 : NB - 1;
            const int qs = segStart[m][lo] >> 2;
            const int qe = segStart[m][hi + 1] >> 2;
            const int qo0 = segStart[m][ib] >> 2;       // own-bucket quad range
            const int qo1 = segStart[m][ib + 1] >> 2;   // (bucket pads are 4-aligned)
            const float eWm = eW[m], k1m = kap1[m];
            const uint2* cqp = CqW + m * QCAP * 3;
            uint2 w0 = make_uint2(0u, 0u), w1 = w0, w2 = w0;
            if (qs < qe) { const uint2* p = cqp + 3 * qs; w0 = p[0]; w1 = p[1]; w2 = p[2]; }
            for (int q = qs; q < qe; ++q) {
                const uint2 n0 = w0, n1 = w1, n2 = w2;
                {   // prefetch next quad's coefficients (redundant last iter)
                    const int qn = (q + 1 < qe) ? q + 1 : q;
                    const uint2* p = cqp + 3 * qn;
                    w0 = p[0]; w1 = p[1]; w2 = p[2];
                }
                const float2 cA01 = __half22float2(reinterpret_cast<const __half2&>(n0.x));
                const float2 cA23 = __half22float2(reinterpret_cast<const __half2&>(n0.y));
                const float2 cB01 = __half22float2(reinterpret_cast<const __half2&>(n1.x));
                const float2 cB23 = __half22float2(reinterpret_cast<const __half2&>(n1.y));
                const float2 cC01 = __half22float2(reinterpret_cast<const __half2&>(n2.x));
                const float2 cC23 = __half22float2(reinterpret_cast<const __half2&>(n2.y));
                const float fc = (q < qo0) ? eWm : ((q >= qo1) ? k1m : 1.0f);
#pragma unroll
                for (int i = 0; i < 4; ++i) {
                    const float xs = xb[i] * fc;
                    float t = xs + cA01.x;
                    t = fmaf(t, xs, cA01.y); t = fmaf(t, xs, cA23.x);
                    const float D = fmaf(t, xs, cA23.y);
                    float u = fmaf(cB01.x, xs, cB01.y); u = fmaf(u, xs, cB23.x);
                    const float NA = fmaf(u, xs, cB23.y);
                    float v = fmaf(cC01.x, xs, cC01.y); v = fmaf(v, xs, cC23.x);
                    const float NP = fmaf(v, xs, cC23.y);
                    const float rd = __builtin_amdgcn_rcpf(D);
                    AN[m][i] = fmaf(NA, rd, AN[m][i]);
                    AP[m][i] = fmaf(NP, rd, AP[m][i]);
                }
            }
            // out-of-band tails
#pragma unroll
            for (int i = 0; i < 4; ++i) {
                const float eb = xb[i];
                const float rb = __builtin_amdgcn_rcpf(eb);
                const float tq = rb * kap2[m], sq = eb * kap2[m];
                const float tq2 = tq * tq, sq2 = sq * sq;
                AN[m][i] += tq * Tab[m][0][0][ib] - tq2 * Tab[m][0][1][ib]
                          + Tab[m][0][4][ib+4] - sq * Tab[m][0][2][ib+4] + sq2 * Tab[m][0][3][ib+4];
                AP[m][i] += tq * Tab[m][1][0][ib] - tq2 * Tab[m][1][1][ib]
                          + Tab[m][1][4][ib+4] - sq * Tab[m][1][2][ib+4] + sq2 * Tab[m][1][3][ib+4];
            }
        }
    }
    __syncthreads();   // En/Cq dead -> overlay A onto the pool

    // ---- Phase 5: unscatter to original columns ----
    float* A0 = (float*)pool;
    float* A1 = A0 + 1025;
    float* A2 = A1 + 1025;
    float* A3 = A2 + 1025;
#pragma unroll
    for (int i = 0; i < 4; ++i) {
        const int oiV = Idx[0][s0i + i];
        const int oiL = Idx[1][s0i + i];
        A0[oiV] = AN[0][i]; A1[oiV] = AP[0][i];
        A2[oiL] = AN[1][i]; A3[oiL] = AP[1][i];
    }
    __syncthreads();

    // ---- Phase 6: epilogue ----
#pragma unroll
    for (int i = 0; i < 4; ++i) {
        const int c = tid + i * NT;
        const bool pf = (cat[i] & 1) != 0;
        const bool nf = (cat[i] & 2) != 0;
        const float rkv = (pf ? 1.f + A0[c] : 0.f) + (nf ? 1.f + A1[c] : 0.f);
        const float rkl = (pf ? 1.f + A2[c] : 0.f) + (nf ? 1.f + A3[c] : 0.f);
        out[r * B + c] = 61.f * (w_v[r * B + c] / (60.f + rkv) +
                                 w_l[r * B + c] / (60.f + rkl));
    }
}

extern "C" void kernel_launch(void* const* d_in, const int* in_sizes, int n_in,
                              void* d_out, int out_size, void* d_ws, size_t ws_size,
                              hipStream_t stream) {
    const float* s_v = (const float*)d_in[0];
    const float* s_l = (const float*)d_in[1];
    const int* pos_mask = (const int*)d_in[2];
    const int* neg_mask = (const int*)d_in[3];
    const float* w_v = (const float*)d_in[4];
    const float* w_l = (const float*)d_in[5];
    float* out = (float*)d_out;

    rank_band2_kernel<<<B, NT, 0, stream>>>(s_v, s_l, pos_mask, neg_mask,
                                            w_v, w_l, out);
}

// Round 10
// 96.210 us; speedup vs baseline: 1.2616x; 1.0068x over previous
//
#include <hip/hip_runtime.h>

// DifferentiableRankIntegration, B=1024, tau=0.1, K=60.
// R10 = R9's verified band algorithm, one block per (row, matrix):
//  - value-bucket compaction (NB=25, W>=3), bucket-local en = e^{u-c_bkt}
//  - in-band (ib-1..ib+1): exact weighted quartic rational, 1 rcp / 4 terms
//  - out-of-band: 2-term sigma tail -> geometric prefix/suffix tables
// Block writes rank_m[r][c] to workspace; combine kernel fuses the epilogue.
// LDS ~24KB -> 6 blocks/CU; 2048 blocks = 8/CU total (imbalance hidden).

constexpr int B = 1024;
constexpr int NT = 256;
constexpr int NB = 25;
constexpr int SLOTCAP = 1104;     // 1024 + up to 75 pads (pad-4 per bucket)
constexpr int QCAP = SLOTCAP / 4; // 276
constexpr int DUMP = 1024;
constexpr float L2E = 1.4426950408889634f;

constexpr int CQ_FLOATS = 6 * QCAP * 2;   // 6 float2 arrays = 3312 floats
// A-overlay needs 2*1025 = 2050 floats <= 3312  ✓

__global__ __launch_bounds__(NT, 6)
void rank_one_kernel(const float* __restrict__ s_v, const float* __restrict__ s_l,
                     const int* __restrict__ pos_m, const int* __restrict__ neg_m,
                     float* __restrict__ rank_ws) {
    __shared__ __align__(16) float En[SLOTCAP];
    __shared__ __align__(16) float CqA[CQ_FLOATS];   // phase A: Cq; phase B: A0/A1
    __shared__ unsigned short Idx[SLOTCAP];
    __shared__ unsigned char Flg[SLOTCAP];           // cat (0 = dummy/pad)
    __shared__ unsigned char BktQ[QCAP];
    __shared__ int segCnt[NB][16];
    __shared__ int segStart[NB + 1];
    __shared__ float Tab[2][5][32];   // [cls AN/AP][P1,P2,Q1,Q2,S0][bkt+2]
    __shared__ float Red[2][4];

    const int m = blockIdx.x >> 10;
    const int r = blockIdx.x & 1023;
    const float* __restrict__ S = m ? s_l : s_v;
    const int tid = threadIdx.x;
    const int lane = tid & 63;
    const int wvid = tid >> 6;
    const unsigned long long lmask = (1ull << lane) - 1ull;

    for (int s = tid; s < SLOTCAP; s += NT) {
        En[s] = 0.f; Idx[s] = DUMP; Flg[s] = 0;
    }
    for (int s = tid; s < 2 * 5 * 32; s += NT) ((float*)Tab)[s] = 0.f;
    __syncthreads();

    // ---- Phase 1: read, u = s/tau, cat, row min/max ----
    float uu[4]; int cat[4];
    float mn = 1e30f, mx = -1e30f;
#pragma unroll
    for (int i = 0; i < 4; ++i) {
        const int c = tid + i * NT;
        uu[i] = S[r * B + c] * 10.0f;
        const int pf = pos_m[r * B + c] != 0, nf = neg_m[r * B + c] != 0;
        cat[i] = pf | (nf << 1);
        mn = fminf(mn, uu[i]); mx = fmaxf(mx, uu[i]);
    }
#pragma unroll
    for (int off = 1; off < 64; off <<= 1) {
        mn = fminf(mn, __shfl_xor(mn, off));
        mx = fmaxf(mx, __shfl_xor(mx, off));
    }
    if (lane == 0) { Red[0][wvid] = mn; Red[1][wvid] = mx; }
    __syncthreads();

    const float lo = fminf(fminf(Red[0][0], Red[0][1]), fminf(Red[0][2], Red[0][3]));
    const float hi = fmaxf(fmaxf(Red[1][0], Red[1][1]), fmaxf(Red[1][2], Red[1][3]));
    const float umin = lo;
    const float Wb   = fmaxf((hi - lo) * (1.0001f / NB), 3.0f);
    const float invW = 1.0f / Wb;
    const float kap1 = exp2f(-Wb * L2E);
    const float kap2 = kap1 * kap1;
    const float eWm  = exp2f(Wb * L2E);

    // ---- Phase 1b: bucket keys + deterministic ballot counts ----
    int key[4], rk[4];
#pragma unroll
    for (int i = 0; i < 4; ++i) {
        int b = (int)((uu[i] - umin) * invW);
        b = b > NB - 1 ? NB - 1 : b;
        key[i] = cat[i] ? b : -1;
        rk[i] = 0;
        for (int k = 0; k < NB; ++k) {
            unsigned long long bl = __ballot(key[i] == k);
            if (key[i] == k) rk[i] = (int)__popcll(bl & lmask);
            if (lane == 0) segCnt[k][i * 4 + wvid] = (int)__popcll(bl);
        }
    }
    __syncthreads();

    // ---- Phase 2a: padded lengths -> prefix starts ----
    if (tid < NB) {
        int t = 0;
#pragma unroll
        for (int u = 0; u < 16; ++u) t += segCnt[tid][u];
        segStart[tid] = (t + 3) & ~3;
    }
    __syncthreads();
    if (tid == 0) {
        int run = 0;
        for (int k = 0; k < NB; ++k) { int t = segStart[k]; segStart[k] = run; run += t; }
        segStart[NB] = run;
    }
    __syncthreads();

    // ---- Phase 2b: placement (bucket-local normalized E) ----
#pragma unroll
    for (int i = 0; i < 4; ++i) {
        if (cat[i]) {
            const int k = key[i];
            const int unit = i * 4 + wvid;
            int pre = 0;
            for (int u = 0; u < unit; ++u) pre += segCnt[k][u];
            const int slot = segStart[k] + pre + rk[i];
            const float cb = umin + ((float)k + 0.5f) * Wb;
            En[slot] = exp2f((uu[i] - cb) * L2E);
            Idx[slot] = (unsigned short)(tid + i * NT);
            Flg[slot] = (unsigned char)cat[i];
        }
    }
    __syncthreads();

    const int nS = segStart[NB];
    const int nQ = nS >> 2;

    // ---- Phase 3a: quad coefficients (f32, SoA float2 arrays) ----
    float2* Cq2 = (float2*)CqA;   // Cq2[j * QCAP + q], j = 0..5
    for (int q = tid; q < nQ; q += NT) {
        int bq = 0;
        for (int k = 1; k < NB; ++k) bq += (4 * q >= segStart[k]);
        BktQ[q] = (unsigned char)bq;
        const float4 e4v = *(const float4*)&En[4 * q];
        const uchar4 f4 = *(const uchar4*)&Flg[4 * q];
        const float en[4] = {e4v.x, e4v.y, e4v.z, e4v.w};
        const int fl[4] = {f4.x, f4.y, f4.z, f4.w};
        const float s01 = en[0] + en[1], p01 = en[0] * en[1];
        const float s23 = en[2] + en[3], p23 = en[2] * en[3];
        const float e1 = s01 + s23;
        const float e2 = fmaf(s01, s23, p01 + p23);
        const float e3 = fmaf(s01, p23, s23 * p01);
        const float e4 = p01 * p23;
        float nA3 = 0.f, nA2 = 0.f, nA1 = 0.f, nA0 = 0.f;
        float nP3 = 0.f, nP2 = 0.f, nP1 = 0.f, nP0 = 0.f;
#pragma unroll
        for (int j = 0; j < 4; ++j) {
            const float b1 = e1 - en[j];
            const float b2 = fmaf(-en[j], b1, e2);
            const float b3 = fmaf(-en[j], b2, e3);
            const float nn = (float)(fl[j] >> 1) * en[j];
            const float pp = (float)(fl[j] & 1) * en[j];
            nA3 += nn; nA2 = fmaf(nn, b1, nA2); nA1 = fmaf(nn, b2, nA1); nA0 = fmaf(nn, b3, nA0);
            nP3 += pp; nP2 = fmaf(pp, b1, nP2); nP1 = fmaf(pp, b2, nP1); nP0 = fmaf(pp, b3, nP0);
        }
        Cq2[0 * QCAP + q] = make_float2(e1, e2);
        Cq2[1 * QCAP + q] = make_float2(e3, e4);
        Cq2[2 * QCAP + q] = make_float2(nA3, nA2);
        Cq2[3 * QCAP + q] = make_float2(nA1, nA0);
        Cq2[4 * QCAP + q] = make_float2(nP3, nP2);
        Cq2[5 * QCAP + q] = make_float2(nP1, nP0);
    }
    // ---- Phase 3b: per-bucket tail sums ----
    if (tid < NB) {
        const int k = tid;
        float g1a=0,g2a=0,h1a=0,h2a=0,s0a=0, g1p=0,g2p=0,h1p=0,h2p=0,s0p=0;
        for (int s = segStart[k]; s < segStart[k + 1]; ++s) {
            const int f = Flg[s];
            if (!f) continue;
            const float en = En[s];
            const float ren = __builtin_amdgcn_rcpf(en);
            const float nf = (float)(f >> 1), pf = (float)(f & 1);
            g1a = fmaf(nf, en, g1a);  g2a = fmaf(nf, en * en, g2a);
            h1a = fmaf(nf, ren, h1a); h2a = fmaf(nf, ren * ren, h2a); s0a += nf;
            g1p = fmaf(pf, en, g1p);  g2p = fmaf(pf, en * en, g2p);
            h1p = fmaf(pf, ren, h1p); h2p = fmaf(pf, ren * ren, h2p); s0p += pf;
        }
        Tab[0][0][k+2]=g1a; Tab[0][1][k+2]=g2a; Tab[0][2][k+2]=h1a; Tab[0][3][k+2]=h2a; Tab[0][4][k+2]=s0a;
        Tab[1][0][k+2]=g1p; Tab[1][1][k+2]=g2p; Tab[1][2][k+2]=h1p; Tab[1][3][k+2]=h2p; Tab[1][4][k+2]=s0p;
    }
    __syncthreads();
    // ---- Phase 3c: geometric prefix/suffix scans ----
    if (tid < 2) {
        const int cls = tid;
        float r1 = 0.f, r2 = 0.f;
        for (int k = 0; k < NB; ++k) {
            r1 = fmaf(r1, kap1, Tab[cls][0][k+2]); Tab[cls][0][k+2] = r1;
            r2 = fmaf(r2, kap2, Tab[cls][1][k+2]); Tab[cls][1][k+2] = r2;
        }
        float q1 = 0.f, q2 = 0.f, s0 = 0.f;
        for (int k = NB - 1; k >= 0; --k) {
            q1 = fmaf(q1, kap1, Tab[cls][2][k+2]); Tab[cls][2][k+2] = q1;
            q2 = fmaf(q2, kap2, Tab[cls][3][k+2]); Tab[cls][3][k+2] = q2;
            s0 += Tab[cls][4][k+2];                Tab[cls][4][k+2] = s0;
        }
    }
    __syncthreads();

    // ---- Phase 4: main — in-band quartic + out-of-band tails ----
    float AN[4] = {0,0,0,0}, AP[4] = {0,0,0,0};
    const int s0i = 4 * tid;
    if (s0i < nS) {
        const float4 x4 = *(const float4*)&En[s0i];
        const float xb[4] = {x4.x, x4.y, x4.z, x4.w};
        const int ib = BktQ[tid];
        const int klo = ib > 0 ? ib - 1 : 0;
        const int khi = ib < NB - 1 ? ib + 1 : NB - 1;
        const int qs = segStart[klo] >> 2;
        const int qe = segStart[khi + 1] >> 2;
        const int qo0 = segStart[ib] >> 2;
        const int qo1 = segStart[ib + 1] >> 2;
        for (int q = qs; q < qe; ++q) {
            const float2 cA = Cq2[0 * QCAP + q];
            const float2 cB = Cq2[1 * QCAP + q];
            const float2 cC = Cq2[2 * QCAP + q];
            const float2 cD = Cq2[3 * QCAP + q];
            const float2 cE = Cq2[4 * QCAP + q];
            const float2 cF = Cq2[5 * QCAP + q];
            const float fc = (q < qo0) ? eWm : ((q >= qo1) ? kap1 : 1.0f);
#pragma unroll
            for (int i = 0; i < 4; ++i) {
                const float xs = xb[i] * fc;
                float t = xs + cA.x;
                t = fmaf(t, xs, cA.y); t = fmaf(t, xs, cB.x);
                const float D = fmaf(t, xs, cB.y);
                float u = fmaf(cC.x, xs, cC.y); u = fmaf(u, xs, cD.x);
                const float NA = fmaf(u, xs, cD.y);
                float v = fmaf(cE.x, xs, cE.y); v = fmaf(v, xs, cF.x);
                const float NP = fmaf(v, xs, cF.y);
                const float rd = __builtin_amdgcn_rcpf(D);
                AN[i] = fmaf(NA, rd, AN[i]);
                AP[i] = fmaf(NP, rd, AP[i]);
            }
        }
        // out-of-band tails
#pragma unroll
        for (int i = 0; i < 4; ++i) {
            const float eb = xb[i];
            const float rb = __builtin_amdgcn_rcpf(eb);
            const float tq = rb * kap2, sq = eb * kap2;
            const float tq2 = tq * tq, sq2 = sq * sq;
            AN[i] += tq * Tab[0][0][ib] - tq2 * Tab[0][1][ib]
                   + Tab[0][4][ib+4] - sq * Tab[0][2][ib+4] + sq2 * Tab[0][3][ib+4];
            AP[i] += tq * Tab[1][0][ib] - tq2 * Tab[1][1][ib]
                   + Tab[1][4][ib+4] - sq * Tab[1][2][ib+4] + sq2 * Tab[1][3][ib+4];
        }
    }
    __syncthreads();   // Cq dead -> overlay A0/A1

    // ---- Phase 5: unscatter to original columns ----
    float* A0 = CqA;
    float* A1 = CqA + 1025;
#pragma unroll
    for (int i = 0; i < 4; ++i) {
        const int oi = Idx[s0i + i];
        A0[oi] = AN[i]; A1[oi] = AP[i];
    }
    __syncthreads();

    // ---- Phase 6: write rank_m ----
#pragma unroll
    for (int i = 0; i < 4; ++i) {
        const int c = tid + i * NT;
        const bool pf = (cat[i] & 1) != 0;
        const bool nf = (cat[i] & 2) != 0;
        const float rk_ = (pf ? 1.f + A0[c] : 0.f) + (nf ? 1.f + A1[c] : 0.f);
        rank_ws[m * (B * B) + r * B + c] = rk_;
    }
}

__global__ __launch_bounds__(NT, 8)
void combine_kernel(const float* __restrict__ rank_ws,
                    const float* __restrict__ w_v, const float* __restrict__ w_l,
                    float* __restrict__ out) {
    const int i4 = (blockIdx.x * NT + threadIdx.x) * 4;
    const float4 rv = *(const float4*)&rank_ws[i4];
    const float4 rl = *(const float4*)&rank_ws[B * B + i4];
    const float4 wv = *(const float4*)&w_v[i4];
    const float4 wl = *(const float4*)&w_l[i4];
    float4 o;
    o.x = 61.f * (wv.x / (60.f + rv.x) + wl.x / (60.f + rl.x));
    o.y = 61.f * (wv.y / (60.f + rv.y) + wl.y / (60.f + rl.y));
    o.z = 61.f * (wv.z / (60.f + rv.z) + wl.z / (60.f + rl.z));
    o.w = 61.f * (wv.w / (60.f + rv.w) + wl.w / (60.f + rl.w));
    *(float4*)&out[i4] = o;
}

extern "C" void kernel_launch(void* const* d_in, const int* in_sizes, int n_in,
                              void* d_out, int out_size, void* d_ws, size_t ws_size,
                              hipStream_t stream) {
    const float* s_v = (const float*)d_in[0];
    const float* s_l = (const float*)d_in[1];
    const int* pos_mask = (const int*)d_in[2];
    const int* neg_mask = (const int*)d_in[3];
    const float* w_v = (const float*)d_in[4];
    const float* w_l = (const float*)d_in[5];
    float* out = (float*)d_out;
    float* rank_ws = (float*)d_ws;   // 2 * 1024 * 1024 floats = 8 MB

    rank_one_kernel<<<2 * B, NT, 0, stream>>>(s_v, s_l, pos_mask, neg_mask, rank_ws);
    combine_kernel<<<(B * B) / (NT * 4), NT, 0, stream>>>(rank_ws, w_v, w_l, out);
}

// Round 13
// 87.522 us; speedup vs baseline: 1.3869x; 1.0993x over previous
//
#include <hip/hip_runtime.h>

// DifferentiableRankIntegration, B=1024, tau=0.1, K=60.
// R11 = R10's verified band algorithm (numerics identical), restructured for
// 8 blocks/CU residency (LDS 24.6K -> 19.4K):
//  - slot[] kept in registers (Idx array dropped; phase-5 rank written BY SLOT,
//    phase-6 reads RankA[slot(c)])
//  - cat packed into En mantissa LSBs (Flg array dropped; pads stay 0.0)
//  - segCnt (dead after phase 2b) overlaid by Tab + BktQ
// Algorithm: value-bucket compaction (NB=25, W>=3), en = e^{u-c_bkt};
// in-band (ib-1..ib+1) exact weighted quartic rational (1 rcp / 4 a-terms,
// numerator via synthetic division); out-of-band 2-term sigma tails via
// geometric prefix/suffix tables. rank written to ws; combine kernel fuses
// the final epilogue.

constexpr int B = 1024;
constexpr int NT = 256;
constexpr int NB = 25;
constexpr int SLOTCAP = 1104;     // 1024 + up to 75 pads (pad-4 per bucket)
constexpr int QCAP = SLOTCAP / 4; // 276
constexpr float L2E = 1.4426950408889634f;

constexpr int OFF_EN  = 0;                       // SLOTCAP f32 = 4416 B
constexpr int OFF_CQ  = SLOTCAP * 4;             // 6*QCAP float2 = 13248 B
                                                 //  (phase>=5: RankA/RankP 8832 B)
constexpr int OFF_SEG = OFF_CQ + 6 * QCAP * 8;   // segCnt 1600 B
                                                 //  (phase>=3: Tab 1280 + BktQ 276)
constexpr int OFF_SST = OFF_SEG + NB * 16 * 4;   // segStart 104 B
constexpr int OFF_RED = OFF_SST + (NB + 1) * 4;  // Red 32 B
constexpr int POOL_BYTES = OFF_RED + 32;         // 19400 B

__global__ __launch_bounds__(NT, 8)
void rank_one_kernel(const float* __restrict__ s_v, const float* __restrict__ s_l,
                     const int* __restrict__ pos_m, const int* __restrict__ neg_m,
                     float* __restrict__ rank_ws) {
    __shared__ __align__(16) char pool[POOL_BYTES];
    float* En        = (float*)(pool + OFF_EN);
    float2* Cq2      = (float2*)(pool + OFF_CQ);
    int (*segCnt)[16]= (int(*)[16])(pool + OFF_SEG);
    float* TabF      = (float*)(pool + OFF_SEG);               // [2][5][32] overlay
    unsigned char* BktQ = (unsigned char*)(pool + OFF_SEG + 1280);
    int* segStart    = (int*)(pool + OFF_SST);                 // [NB+1]
    float* Red       = (float*)(pool + OFF_RED);               // [2][4]
    float* RankA     = (float*)(pool + OFF_CQ);                // phase>=5 overlay
    float* RankP     = RankA + SLOTCAP;

    const int m = blockIdx.x >> 10;
    const int r = blockIdx.x & 1023;
    const float* __restrict__ S = m ? s_l : s_v;
    const int tid = threadIdx.x;
    const int lane = tid & 63;
    const int wvid = tid >> 6;
    const unsigned long long lmask = (1ull << lane) - 1ull;

    for (int s = tid; s < SLOTCAP; s += NT) En[s] = 0.f;   // pads = 0.0 (cat bits 0)
    __syncthreads();

    // ---- Phase 1: read, u = s/tau, cat, row min/max ----
    float uu[4]; int cat[4];
    float mn = 1e30f, mx = -1e30f;
#pragma unroll
    for (int i = 0; i < 4; ++i) {
        const int c = tid + i * NT;
        uu[i] = S[r * B + c] * 10.0f;
        const int pf = pos_m[r * B + c] != 0, nf = neg_m[r * B + c] != 0;
        cat[i] = pf | (nf << 1);
        mn = fminf(mn, uu[i]); mx = fmaxf(mx, uu[i]);
    }
#pragma unroll
    for (int off = 1; off < 64; off <<= 1) {
        mn = fminf(mn, __shfl_xor(mn, off));
        mx = fmaxf(mx, __shfl_xor(mx, off));
    }
    if (lane == 0) { Red[0 * 4 + wvid] = mn; Red[1 * 4 + wvid] = mx; }
    __syncthreads();

    const float lo = fminf(fminf(Red[0], Red[1]), fminf(Red[2], Red[3]));
    const float hi = fmaxf(fmaxf(Red[4], Red[5]), fmaxf(Red[6], Red[7]));
    const float umin = lo;
    const float Wb   = fmaxf((hi - lo) * (1.0001f / NB), 3.0f);
    const float invW = 1.0f / Wb;
    const float kap1 = exp2f(-Wb * L2E);
    const float kap2 = kap1 * kap1;
    const float eWm  = exp2f(Wb * L2E);

    // ---- Phase 1b: bucket keys + deterministic ballot counts ----
    int key[4], rk[4];
#pragma unroll
    for (int i = 0; i < 4; ++i) {
        int b = (int)((uu[i] - umin) * invW);
        b = b > NB - 1 ? NB - 1 : b;
        key[i] = cat[i] ? b : -1;
        rk[i] = 0;
        for (int k = 0; k < NB; ++k) {
            unsigned long long bl = __ballot(key[i] == k);
            if (key[i] == k) rk[i] = (int)__popcll(bl & lmask);
            if (lane == 0) segCnt[k][i * 4 + wvid] = (int)__popcll(bl);
        }
    }
    __syncthreads();

    // ---- Phase 2a: padded lengths -> prefix starts ----
    if (tid < NB) {
        int t = 0;
#pragma unroll
        for (int u = 0; u < 16; ++u) t += segCnt[tid][u];
        segStart[tid] = (t + 3) & ~3;
    }
    __syncthreads();
    if (tid == 0) {
        int run = 0;
        for (int k = 0; k < NB; ++k) { int t = segStart[k]; segStart[k] = run; run += t; }
        segStart[NB] = run;
    }
    __syncthreads();

    // ---- Phase 2b: placement; slot kept in registers; cat packed in En LSBs ----
    int slot[4];
#pragma unroll
    for (int i = 0; i < 4; ++i) {
        slot[i] = 0;
        if (cat[i]) {
            const int k = key[i];
            const int unit = i * 4 + wvid;
            int pre = 0;
            for (int u = 0; u < unit; ++u) pre += segCnt[k][u];
            slot[i] = segStart[k] + pre + rk[i];
            const float cb = umin + ((float)k + 0.5f) * Wb;
            const float env = exp2f((uu[i] - cb) * L2E);
            unsigned eb = __float_as_uint(env);
            eb = (eb & ~3u) | (unsigned)cat[i];
            En[slot[i]] = __uint_as_float(eb);
        }
    }
    __syncthreads();     // segCnt dead from here -> Tab/BktQ overlay valid

    const int nS = segStart[NB];
    const int nQ = nS >> 2;

    // ---- Phase 3a: Tab boundary zeros (disjoint from 3b's [2..26] writes),
    //      quad coefficients (f32, SoA float2 arrays), BktQ ----
    if (tid < 70) {                       // 10 rows x {0,1,27..31}
        const int row = tid / 7, bi = tid % 7;
        TabF[row * 32 + (bi < 2 ? bi : 25 + bi)] = 0.f;
    }
    for (int q = tid; q < nQ; q += NT) {
        int bq = 0;
        for (int k = 1; k < NB; ++k) bq += (4 * q >= segStart[k]);
        BktQ[q] = (unsigned char)bq;
        const float4 e4v = *(const float4*)&En[4 * q];
        const float en[4] = {e4v.x, e4v.y, e4v.z, e4v.w};
        const int fl[4] = {(int)(__float_as_uint(e4v.x) & 3u),
                           (int)(__float_as_uint(e4v.y) & 3u),
                           (int)(__float_as_uint(e4v.z) & 3u),
                           (int)(__float_as_uint(e4v.w) & 3u)};
        const float s01 = en[0] + en[1], p01 = en[0] * en[1];
        const float s23 = en[2] + en[3], p23 = en[2] * en[3];
        const float e1 = s01 + s23;
        const float e2 = fmaf(s01, s23, p01 + p23);
        const float e3 = fmaf(s01, p23, s23 * p01);
        const float e4 = p01 * p23;
        float nA3 = 0.f, nA2 = 0.f, nA1 = 0.f, nA0 = 0.f;
        float nP3 = 0.f, nP2 = 0.f, nP1 = 0.f, nP0 = 0.f;
#pragma unroll
        for (int j = 0; j < 4; ++j) {
            const float b1 = e1 - en[j];
            const float b2 = fmaf(-en[j], b1, e2);
            const float b3 = fmaf(-en[j], b2, e3);
            const float nn = (float)(fl[j] >> 1) * en[j];
            const float pp = (float)(fl[j] & 1) * en[j];
            nA3 += nn; nA2 = fmaf(nn, b1, nA2); nA1 = fmaf(nn, b2, nA1); nA0 = fmaf(nn, b3, nA0);
            nP3 += pp; nP2 = fmaf(pp, b1, nP2); nP1 = fmaf(pp, b2, nP1); nP0 = fmaf(pp, b3, nP0);
        }
        Cq2[0 * QCAP + q] = make_float2(e1, e2);
        Cq2[1 * QCAP + q] = make_float2(e3, e4);
        Cq2[2 * QCAP + q] = make_float2(nA3, nA2);
        Cq2[3 * QCAP + q] = make_float2(nA1, nA0);
        Cq2[4 * QCAP + q] = make_float2(nP3, nP2);
        Cq2[5 * QCAP + q] = make_float2(nP1, nP0);
    }
    // ---- Phase 3b: per-bucket tail sums ----
    if (tid < NB) {
        const int k = tid;
        float g1a=0,g2a=0,h1a=0,h2a=0,s0a=0, g1p=0,g2p=0,h1p=0,h2p=0,s0p=0;
        for (int s = segStart[k]; s < segStart[k + 1]; ++s) {
            const float en = En[s];
            const int f = (int)(__float_as_uint(en) & 3u);
            if (!f) continue;
            const float ren = __builtin_amdgcn_rcpf(en);
            const float nf = (float)(f >> 1), pf = (float)(f & 1);
            g1a = fmaf(nf, en, g1a);  g2a = fmaf(nf, en * en, g2a);
            h1a = fmaf(nf, ren, h1a); h2a = fmaf(nf, ren * ren, h2a); s0a += nf;
            g1p = fmaf(pf, en, g1p);  g2p = fmaf(pf, en * en, g2p);
            h1p = fmaf(pf, ren, h1p); h2p = fmaf(pf, ren * ren, h2p); s0p += pf;
        }
        TabF[(0*5+0)*32 + k+2]=g1a; TabF[(0*5+1)*32 + k+2]=g2a; TabF[(0*5+2)*32 + k+2]=h1a;
        TabF[(0*5+3)*32 + k+2]=h2a; TabF[(0*5+4)*32 + k+2]=s0a;
        TabF[(1*5+0)*32 + k+2]=g1p; TabF[(1*5+1)*32 + k+2]=g2p; TabF[(1*5+2)*32 + k+2]=h1p;
        TabF[(1*5+3)*32 + k+2]=h2p; TabF[(1*5+4)*32 + k+2]=s0p;
    }
    __syncthreads();
    // ---- Phase 3c: geometric prefix/suffix scans ----
    if (tid < 2) {
        const int cls = tid;
        float r1 = 0.f, r2 = 0.f;
        for (int k = 0; k < NB; ++k) {
            r1 = fmaf(r1, kap1, TabF[(cls*5+0)*32 + k+2]); TabF[(cls*5+0)*32 + k+2] = r1;
            r2 = fmaf(r2, kap2, TabF[(cls*5+1)*32 + k+2]); TabF[(cls*5+1)*32 + k+2] = r2;
        }
        float q1 = 0.f, q2 = 0.f, s0 = 0.f;
        for (int k = NB - 1; k >= 0; --k) {
            q1 = fmaf(q1, kap1, TabF[(cls*5+2)*32 + k+2]); TabF[(cls*5+2)*32 + k+2] = q1;
            q2 = fmaf(q2, kap2, TabF[(cls*5+3)*32 + k+2]); TabF[(cls*5+3)*32 + k+2] = q2;
            s0 += TabF[(cls*5+4)*32 + k+2];                TabF[(cls*5+4)*32 + k+2] = s0;
        }
    }
    __syncthreads();

    // ---- Phase 4: main — in-band quartic + out-of-band tails ----
    float AN[4] = {0,0,0,0}, AP[4] = {0,0,0,0};
    const int s0i = 4 * tid;
    if (s0i < nS) {
        const float4 x4 = *(const float4*)&En[s0i];
        const float xb[4] = {x4.x, x4.y, x4.z, x4.w};
        const int ib = BktQ[tid];
        const int klo = ib > 0 ? ib - 1 : 0;
        const int khi = ib < NB - 1 ? ib + 1 : NB - 1;
        const int qs = segStart[klo] >> 2;
        const int qe = segStart[khi + 1] >> 2;
        const int qo0 = segStart[ib] >> 2;
        const int qo1 = segStart[ib + 1] >> 2;
        for (int q = qs; q < qe; ++q) {
            const float2 cA = Cq2[0 * QCAP + q];
            const float2 cB = Cq2[1 * QCAP + q];
            const float2 cC = Cq2[2 * QCAP + q];
            const float2 cD = Cq2[3 * QCAP + q];
            const float2 cE = Cq2[4 * QCAP + q];
            const float2 cF = Cq2[5 * QCAP + q];
            const float fc = (q < qo0) ? eWm : ((q >= qo1) ? kap1 : 1.0f);
#pragma unroll
            for (int i = 0; i < 4; ++i) {
                const float xs = xb[i] * fc;
                float t = xs + cA.x;
                t = fmaf(t, xs, cA.y); t = fmaf(t, xs, cB.x);
                const float D = fmaf(t, xs, cB.y);
                float u = fmaf(cC.x, xs, cC.y); u = fmaf(u, xs, cD.x);
                const float NA = fmaf(u, xs, cD.y);
                float v = fmaf(cE.x, xs, cE.y); v = fmaf(v, xs, cF.x);
                const float NP = fmaf(v, xs, cF.y);
                const float rd = __builtin_amdgcn_rcpf(D);
                AN[i] = fmaf(NA, rd, AN[i]);
                AP[i] = fmaf(NP, rd, AP[i]);
            }
        }
        // out-of-band tails
#pragma unroll
        for (int i = 0; i < 4; ++i) {
            const float eb = xb[i];
            const float rb = __builtin_amdgcn_rcpf(eb);
            const float tq = rb * kap2, sq = eb * kap2;
            const float tq2 = tq * tq, sq2 = sq * sq;
            AN[i] += tq * TabF[(0*5+0)*32 + ib] - tq2 * TabF[(0*5+1)*32 + ib]
                   + TabF[(0*5+4)*32 + ib+4] - sq * TabF[(0*5+2)*32 + ib+4]
                   + sq2 * TabF[(0*5+3)*32 + ib+4];
            AP[i] += tq * TabF[(1*5+0)*32 + ib] - tq2 * TabF[(1*5+1)*32 + ib]
                   + TabF[(1*5+4)*32 + ib+4] - sq * TabF[(1*5+2)*32 + ib+4]
                   + sq2 * TabF[(1*5+3)*32 + ib+4];
        }
    }
    __syncthreads();   // Cq dead -> overlay RankA/RankP

    // ---- Phase 5: write ranks BY SLOT (consecutive, no scatter) ----
#pragma unroll
    for (int i = 0; i < 4; ++i) {
        RankA[s0i + i] = AN[i];
        RankP[s0i + i] = AP[i];
    }
    __syncthreads();

    // ---- Phase 6: gather via register slot[], write rank_m ----
#pragma unroll
    for (int i = 0; i < 4; ++i) {
        const int c = tid + i * NT;
        const bool pf = (cat[i] & 1) != 0;
        const bool nf = (cat[i] & 2) != 0;
        const float rk_ = (pf ? 1.f + RankA[slot[i]] : 0.f) +
                          (nf ? 1.f + RankP[slot[i]] : 0.f);
        rank_ws[m * (B * B) + r * B + c] = rk_;
    }
}

__global__ __launch_bounds__(NT, 8)
void combine_kernel(const float* __restrict__ rank_ws,
                    const float* __restrict__ w_v, const float* __restrict__ w_l,
                    float* __restrict__ out) {
    const int i4 = (blockIdx.x * NT + threadIdx.x) * 4;
    const float4 rv = *(const float4*)&rank_ws[i4];
    const float4 rl = *(const float4*)&rank_ws[B * B + i4];
    const float4 wv = *(const float4*)&w_v[i4];
    const float4 wl = *(const float4*)&w_l[i4];
    float4 o;
    o.x = 61.f * (wv.x / (60.f + rv.x) + wl.x / (60.f + rl.x));
    o.y = 61.f * (wv.y / (60.f + rv.y) + wl.y / (60.f + rl.y));
    o.z = 61.f * (wv.z / (60.f + rv.z) + wl.z / (60.f + rl.z));
    o.w = 61.f * (wv.w / (60.f + rv.w) + wl.w / (60.f + rl.w));
    *(float4*)&out[i4] = o;
}

extern "C" void kernel_launch(void* const* d_in, const int* in_sizes, int n_in,
                              void* d_out, int out_size, void* d_ws, size_t ws_size,
                              hipStream_t stream) {
    const float* s_v = (const float*)d_in[0];
    const float* s_l = (const float*)d_in[1];
    const int* pos_mask = (const int*)d_in[2];
    const int* neg_mask = (const int*)d_in[3];
    const float* w_v = (const float*)d_in[4];
    const float* w_l = (const float*)d_in[5];
    float* out = (float*)d_out;
    float* rank_ws = (float*)d_ws;   // 2 * 1024 * 1024 floats = 8 MB

    rank_one_kernel<<<2 * B, NT, 0, stream>>>(s_v, s_l, pos_mask, neg_mask, rank_ws);
    combine_kernel<<<(B * B) / (NT * 4), NT, 0, stream>>>(rank_ws, w_v, w_l, out);
}

// Round 15
// 76.845 us; speedup vs baseline: 1.5796x; 1.1389x over previous
//
#include <hip/hip_runtime.h>
#include <hip/hip_fp16.h>

// DifferentiableRankIntegration, B=1024, tau=0.1, K=60.
// R15 = R14 with the Tab boundary-zero race fixed (cols {0,1,32..35}, disjoint
// from phase-3b's {2..31}). NB=30 / W>=2.2 + 3-term tails; fc-range-split
// q-loop (hoisted xs); 8-way-parallel per-bucket tail sums; fp16-packed
// numerator coeffs; pool ~16.9KB -> 8 blocks/CU.
// Algorithm: value-bucket compaction, en = e^{u-c_bkt} (cat in mantissa LSBs);
// in-band (ib-1..ib+1): exact weighted quartic rational (1 rcp / 4 a-terms,
// numerators via synthetic division); out-of-band: 3-term sigma tails via
// geometric prefix/suffix tables (kappa^1,2,3 recurrences).

constexpr int B = 1024;
constexpr int NT = 256;
constexpr int NB = 30;
constexpr int SLOTCAP = 1120;      // 1024 + 3*NB pads, rounded to 16
constexpr int QCAP = SLOTCAP / 4;  // 280
constexpr float L2E = 1.4426950408889634f;

constexpr int OFF_EN  = 0;                        // 4480 B
constexpr int OFF_CQ  = OFF_EN + SLOTCAP * 4;     // 4 SoA arrays*QCAP*8 = 8960 B
                                                  //  (phase>=5: RankA/P 8960 B)
constexpr int OFF_SEG = OFF_CQ + 4 * QCAP * 8;    // segCnt ushort[NB][16] = 960 B
constexpr int OFF_TAB = OFF_SEG + NB * 16 * 2;    // Tab 14 rows x 36 cols = 2016 B
constexpr int OFF_BKQ = OFF_TAB + 14 * 36 * 4;    // BktQ QCAP = 280 B
constexpr int OFF_SST = OFF_BKQ + QCAP;           // segStart (NB+1)*4
constexpr int OFF_RED = OFF_SST + (NB + 1) * 4;   // Red 32 B
constexpr int POOL_BYTES = OFF_RED + 32;          // 16852 B

__global__ __launch_bounds__(NT, 8)
void rank_one_kernel(const float* __restrict__ s_v, const float* __restrict__ s_l,
                     const int* __restrict__ pos_m, const int* __restrict__ neg_m,
                     float* __restrict__ rank_ws) {
    __shared__ __align__(16) char pool[POOL_BYTES];
    float* En          = (float*)(pool + OFF_EN);
    float2* Ce12       = (float2*)(pool + OFF_CQ);
    float2* Ce34       = Ce12 + QCAP;
    uint2* ChA         = (uint2*)(Ce34 + QCAP);
    uint2* ChP         = ChA + QCAP;
    unsigned short (*segCnt)[16] = (unsigned short(*)[16])(pool + OFF_SEG);
    float* TabF        = (float*)(pool + OFF_TAB);   // [cls*7+row][36]
    unsigned char* BktQ = (unsigned char*)(pool + OFF_BKQ);
    int* segStart      = (int*)(pool + OFF_SST);
    float* Red         = (float*)(pool + OFF_RED);
    float* RankA       = (float*)(pool + OFF_CQ);    // phase>=5 overlay
    float* RankP       = RankA + SLOTCAP;

    const int m = blockIdx.x >> 10;
    const int r = blockIdx.x & 1023;
    const float* __restrict__ S = m ? s_l : s_v;
    const int tid = threadIdx.x;
    const int lane = tid & 63;
    const int wvid = tid >> 6;
    const unsigned long long lmask = (1ull << lane) - 1ull;

    for (int s = tid; s < SLOTCAP; s += NT) En[s] = 0.f;  // pads: cat bits 0
    __syncthreads();

    // ---- Phase 1: read, u = s/tau, cat, row min/max ----
    float uu[4]; int cat[4];
    float mn = 1e30f, mx = -1e30f;
#pragma unroll
    for (int i = 0; i < 4; ++i) {
        const int c = tid + i * NT;
        uu[i] = S[r * B + c] * 10.0f;
        const int pf = pos_m[r * B + c] != 0, nf = neg_m[r * B + c] != 0;
        cat[i] = pf | (nf << 1);
        mn = fminf(mn, uu[i]); mx = fmaxf(mx, uu[i]);
    }
#pragma unroll
    for (int off = 1; off < 64; off <<= 1) {
        mn = fminf(mn, __shfl_xor(mn, off));
        mx = fmaxf(mx, __shfl_xor(mx, off));
    }
    if (lane == 0) { Red[wvid] = mn; Red[4 + wvid] = mx; }
    __syncthreads();

    const float lo = fminf(fminf(Red[0], Red[1]), fminf(Red[2], Red[3]));
    const float hi = fmaxf(fmaxf(Red[4], Red[5]), fmaxf(Red[6], Red[7]));
    const float umin = lo;
    const float Wb   = fmaxf((hi - lo) * (1.0001f / NB), 2.2f);
    const float invW = 1.0f / Wb;
    const float kap1 = exp2f(-Wb * L2E);
    const float kap2 = kap1 * kap1;
    const float kap3 = kap2 * kap1;
    const float eWm  = exp2f(Wb * L2E);

    // ---- Phase 1b: bucket keys + deterministic ballot counts ----
    int key[4], rk[4];
#pragma unroll
    for (int i = 0; i < 4; ++i) {
        int b = (int)((uu[i] - umin) * invW);
        b = b > NB - 1 ? NB - 1 : b;
        key[i] = cat[i] ? b : -1;
        rk[i] = 0;
        for (int k = 0; k < NB; ++k) {
            unsigned long long bl = __ballot(key[i] == k);
            if (key[i] == k) rk[i] = (int)__popcll(bl & lmask);
            if (lane == 0) segCnt[k][i * 4 + wvid] = (unsigned short)__popcll(bl);
        }
    }
    __syncthreads();

    // ---- Phase 2a: padded lengths -> prefix starts ----
    if (tid < NB) {
        int t = 0;
#pragma unroll
        for (int u = 0; u < 16; ++u) t += (int)segCnt[tid][u];
        segStart[tid] = (t + 3) & ~3;
    }
    __syncthreads();
    if (tid == 0) {
        int run = 0;
        for (int k = 0; k < NB; ++k) { int t = segStart[k]; segStart[k] = run; run += t; }
        segStart[NB] = run;
    }
    __syncthreads();

    // ---- Phase 2b: placement; slot in registers; cat in En mantissa LSBs ----
    int slot[4];
#pragma unroll
    for (int i = 0; i < 4; ++i) {
        slot[i] = 0;
        if (cat[i]) {
            const int k = key[i];
            const int unit = i * 4 + wvid;
            int pre = 0;
            for (int u = 0; u < unit; ++u) pre += (int)segCnt[k][u];
            slot[i] = segStart[k] + pre + rk[i];
            const float cb = umin + ((float)k + 0.5f) * Wb;
            const float env = exp2f((uu[i] - cb) * L2E);
            unsigned eb = __float_as_uint(env);
            eb = (eb & ~3u) | (unsigned)cat[i];
            En[slot[i]] = __uint_as_float(eb);
        }
    }
    __syncthreads();

    const int nS = segStart[NB];
    const int nQ = nS >> 2;

    // ---- Phase 3a: Tab boundary zeros + quad coefficients + BktQ ----
    if (tid < 14 * 6) {                   // cols {0,1,32,33,34,35} per row
        const int row = tid / 6, ci = tid % 6;
        TabF[row * 36 + (ci < 2 ? ci : ci + 30)] = 0.f;   // disjoint from 3b's 2..31
    }
    for (int q = tid; q < nQ; q += NT) {
        int bq = 0;
        for (int k = 1; k < NB; ++k) bq += (4 * q >= segStart[k]);
        BktQ[q] = (unsigned char)bq;
        const float4 e4v = *(const float4*)&En[4 * q];
        const float en[4] = {e4v.x, e4v.y, e4v.z, e4v.w};
        const int fl[4] = {(int)(__float_as_uint(e4v.x) & 3u),
                           (int)(__float_as_uint(e4v.y) & 3u),
                           (int)(__float_as_uint(e4v.z) & 3u),
                           (int)(__float_as_uint(e4v.w) & 3u)};
        const float s01 = en[0] + en[1], p01 = en[0] * en[1];
        const float s23 = en[2] + en[3], p23 = en[2] * en[3];
        const float e1 = s01 + s23;
        const float e2 = fmaf(s01, s23, p01 + p23);
        const float e3 = fmaf(s01, p23, s23 * p01);
        const float e4 = p01 * p23;
        float nA3 = 0.f, nA2 = 0.f, nA1 = 0.f, nA0 = 0.f;
        float nP3 = 0.f, nP2 = 0.f, nP1 = 0.f, nP0 = 0.f;
#pragma unroll
        for (int j = 0; j < 4; ++j) {
            const float b1 = e1 - en[j];
            const float b2 = fmaf(-en[j], b1, e2);
            const float b3 = fmaf(-en[j], b2, e3);
            const float nn = (float)(fl[j] >> 1) * en[j];
            const float pp = (float)(fl[j] & 1) * en[j];
            nA3 += nn; nA2 = fmaf(nn, b1, nA2); nA1 = fmaf(nn, b2, nA1); nA0 = fmaf(nn, b3, nA0);
            nP3 += pp; nP2 = fmaf(pp, b1, nP2); nP1 = fmaf(pp, b2, nP1); nP0 = fmaf(pp, b3, nP0);
        }
        Ce12[q] = make_float2(e1, e2);
        Ce34[q] = make_float2(e3, e4);
        __half2 hA0 = __floats2half2_rn(nA3, nA2);
        __half2 hA1 = __floats2half2_rn(nA1, nA0);
        __half2 hP0 = __floats2half2_rn(nP3, nP2);
        __half2 hP1 = __floats2half2_rn(nP1, nP0);
        ChA[q] = make_uint2(reinterpret_cast<unsigned&>(hA0), reinterpret_cast<unsigned&>(hA1));
        ChP[q] = make_uint2(reinterpret_cast<unsigned&>(hP0), reinterpret_cast<unsigned&>(hP1));
    }
    // ---- Phase 3b: per-bucket tail sums, 8 threads/bucket + shfl reduce ----
    if (tid < NB * 8) {
        const int k = tid >> 3, o = tid & 7;
        float g1a=0,g2a=0,g3a=0,h1a=0,h2a=0,h3a=0,s0a=0;
        float g1p=0,g2p=0,g3p=0,h1p=0,h2p=0,h3p=0,s0p=0;
        for (int s = segStart[k] + o; s < segStart[k + 1]; s += 8) {
            const float en = En[s];
            const int f = (int)(__float_as_uint(en) & 3u);
            if (!f) continue;
            const float en2 = en * en, en3 = en2 * en;
            const float ren = __builtin_amdgcn_rcpf(en);
            const float ren2 = ren * ren, ren3 = ren2 * ren;
            const float nf = (float)(f >> 1), pf = (float)(f & 1);
            g1a = fmaf(nf,en,g1a);  g2a = fmaf(nf,en2,g2a);  g3a = fmaf(nf,en3,g3a);
            h1a = fmaf(nf,ren,h1a); h2a = fmaf(nf,ren2,h2a); h3a = fmaf(nf,ren3,h3a); s0a += nf;
            g1p = fmaf(pf,en,g1p);  g2p = fmaf(pf,en2,g2p);  g3p = fmaf(pf,en3,g3p);
            h1p = fmaf(pf,ren,h1p); h2p = fmaf(pf,ren2,h2p); h3p = fmaf(pf,ren3,h3p); s0p += pf;
        }
#define RED8(v) v += __shfl_xor(v, 4); v += __shfl_xor(v, 2); v += __shfl_xor(v, 1)
        RED8(g1a); RED8(g2a); RED8(g3a); RED8(h1a); RED8(h2a); RED8(h3a); RED8(s0a);
        RED8(g1p); RED8(g2p); RED8(g3p); RED8(h1p); RED8(h2p); RED8(h3p); RED8(s0p);
#undef RED8
        if (o == 0) {
            TabF[(0*7+0)*36+k+2]=g1a; TabF[(0*7+1)*36+k+2]=g2a; TabF[(0*7+2)*36+k+2]=g3a;
            TabF[(0*7+3)*36+k+2]=h1a; TabF[(0*7+4)*36+k+2]=h2a; TabF[(0*7+5)*36+k+2]=h3a;
            TabF[(0*7+6)*36+k+2]=s0a;
            TabF[(1*7+0)*36+k+2]=g1p; TabF[(1*7+1)*36+k+2]=g2p; TabF[(1*7+2)*36+k+2]=g3p;
            TabF[(1*7+3)*36+k+2]=h1p; TabF[(1*7+4)*36+k+2]=h2p; TabF[(1*7+5)*36+k+2]=h3p;
            TabF[(1*7+6)*36+k+2]=s0p;
        }
    }
    __syncthreads();
    // ---- Phase 3c: geometric prefix/suffix scans, 14-way parallel ----
    if (tid < 14) {
        const int row = tid % 7;
        float* Trow = &TabF[tid * 36];
        if (row < 3) {
            const float kp = row == 0 ? kap1 : (row == 1 ? kap2 : kap3);
            float r1 = 0.f;
            for (int k = 0; k < NB; ++k) { r1 = fmaf(r1, kp, Trow[k+2]); Trow[k+2] = r1; }
        } else if (row < 6) {
            const float kp = row == 3 ? kap1 : (row == 4 ? kap2 : kap3);
            float q1 = 0.f;
            for (int k = NB - 1; k >= 0; --k) { q1 = fmaf(q1, kp, Trow[k+2]); Trow[k+2] = q1; }
        } else {
            float s0 = 0.f;
            for (int k = NB - 1; k >= 0; --k) { s0 += Trow[k+2]; Trow[k+2] = s0; }
        }
    }
    __syncthreads();

    // ---- Phase 4: main — in-band quartic (3 fc-ranges) + 3-term tails ----
    float AN[4] = {0,0,0,0}, AP[4] = {0,0,0,0};
    const int s0i = 4 * tid;
    if (s0i < nS) {
        const float4 x4 = *(const float4*)&En[s0i];
        const float xb[4] = {x4.x, x4.y, x4.z, x4.w};
        const int ib = BktQ[tid];
        const int klo = ib > 0 ? ib - 1 : 0;
        const int khi = ib < NB - 1 ? ib + 1 : NB - 1;
        const int qs  = segStart[klo] >> 2;
        const int qe  = segStart[khi + 1] >> 2;
        const int qo0 = segStart[ib] >> 2;
        const int qo1 = segStart[ib + 1] >> 2;

        auto quadrun = [&](int q0, int q1, const float* xs) {
            for (int q = q0; q < q1; ++q) {
                const float2 e12 = Ce12[q], e34 = Ce34[q];
                const uint2 ha = ChA[q], hp = ChP[q];
                const float2 a01 = __half22float2(*(const __half2*)&ha.x);
                const float2 a23 = __half22float2(*(const __half2*)&ha.y);
                const float2 p01 = __half22float2(*(const __half2*)&hp.x);
                const float2 p23 = __half22float2(*(const __half2*)&hp.y);
#pragma unroll
                for (int i = 0; i < 4; ++i) {
                    const float x = xs[i];
                    float t = x + e12.x; t = fmaf(t, x, e12.y); t = fmaf(t, x, e34.x);
                    const float D = fmaf(t, x, e34.y);
                    float u = fmaf(a01.x, x, a01.y); u = fmaf(u, x, a23.x);
                    const float NA = fmaf(u, x, a23.y);
                    float v = fmaf(p01.x, x, p01.y); v = fmaf(v, x, p23.x);
                    const float NP = fmaf(v, x, p23.y);
                    const float rd = __builtin_amdgcn_rcpf(D);
                    AN[i] = fmaf(NA, rd, AN[i]);
                    AP[i] = fmaf(NP, rd, AP[i]);
                }
            }
        };
        float xsl[4], xsh[4];
#pragma unroll
        for (int i = 0; i < 4; ++i) { xsl[i] = xb[i] * eWm; xsh[i] = xb[i] * kap1; }
        quadrun(qs,  qo0, xsl);   // below-band buckets: fc = e^W
        quadrun(qo0, qo1, xb);    // own bucket: fc = 1
        quadrun(qo1, qe,  xsh);   // above-band buckets: fc = kappa

        // 3-term out-of-band tails (table reads hoisted; ib uniform per thread)
        const float P1a = TabF[(0*7+0)*36+ib],   P2a = TabF[(0*7+1)*36+ib],   P3a = TabF[(0*7+2)*36+ib];
        const float S1a = TabF[(0*7+3)*36+ib+4], S2a = TabF[(0*7+4)*36+ib+4], S3a = TabF[(0*7+5)*36+ib+4];
        const float S0a = TabF[(0*7+6)*36+ib+4];
        const float P1p = TabF[(1*7+0)*36+ib],   P2p = TabF[(1*7+1)*36+ib],   P3p = TabF[(1*7+2)*36+ib];
        const float S1p = TabF[(1*7+3)*36+ib+4], S2p = TabF[(1*7+4)*36+ib+4], S3p = TabF[(1*7+5)*36+ib+4];
        const float S0p = TabF[(1*7+6)*36+ib+4];
#pragma unroll
        for (int i = 0; i < 4; ++i) {
            const float eb = xb[i];
            const float rb = __builtin_amdgcn_rcpf(eb);
            const float tq = rb * kap2, sq = eb * kap2;
            const float tq2 = tq * tq, tq3 = tq2 * tq;
            const float sq2 = sq * sq, sq3 = sq2 * sq;
            AN[i] += tq * P1a - tq2 * P2a + tq3 * P3a
                   + S0a - sq * S1a + sq2 * S2a - sq3 * S3a;
            AP[i] += tq * P1p - tq2 * P2p + tq3 * P3p
                   + S0p - sq * S1p + sq2 * S2p - sq3 * S3p;
        }
    }
    __syncthreads();   // Cq dead -> overlay RankA/RankP

    // ---- Phase 5: write ranks BY SLOT (consecutive) ----
#pragma unroll
    for (int i = 0; i < 4; ++i) {
        RankA[s0i + i] = AN[i];
        RankP[s0i + i] = AP[i];
    }
    __syncthreads();

    // ---- Phase 6: gather via register slot[], write rank_m ----
#pragma unroll
    for (int i = 0; i < 4; ++i) {
        const int c = tid + i * NT;
        const bool pf = (cat[i] & 1) != 0;
        const bool nf = (cat[i] & 2) != 0;
        const float rk_ = (pf ? 1.f + RankA[slot[i]] : 0.f) +
                          (nf ? 1.f + RankP[slot[i]] : 0.f);
        rank_ws[m * (B * B) + r * B + c] = rk_;
    }
}

__global__ __launch_bounds__(NT, 8)
void combine_kernel(const float* __restrict__ rank_ws,
                    const float* __restrict__ w_v, const float* __restrict__ w_l,
                    float* __restrict__ out) {
    const int i4 = (blockIdx.x * NT + threadIdx.x) * 4;
    const float4 rv = *(const float4*)&rank_ws[i4];
    const float4 rl = *(const float4*)&rank_ws[B * B + i4];
    const float4 wv = *(const float4*)&w_v[i4];
    const float4 wl = *(const float4*)&w_l[i4];
    float4 o;
    o.x = 61.f * (wv.x / (60.f + rv.x) + wl.x / (60.f + rl.x));
    o.y = 61.f * (wv.y / (60.f + rv.y) + wl.y / (60.f + rl.y));
    o.z = 61.f * (wv.z / (60.f + rv.z) + wl.z / (60.f + rl.z));
    o.w = 61.f * (wv.w / (60.f + rv.w) + wl.w / (60.f + rl.w));
    *(float4*)&out[i4] = o;
}

extern "C" void kernel_launch(void* const* d_in, const int* in_sizes, int n_in,
                              void* d_out, int out_size, void* d_ws, size_t ws_size,
                              hipStream_t stream) {
    const float* s_v = (const float*)d_in[0];
    const float* s_l = (const float*)d_in[1];
    const int* pos_mask = (const int*)d_in[2];
    const int* neg_mask = (const int*)d_in[3];
    const float* w_v = (const float*)d_in[4];
    const float* w_l = (const float*)d_in[5];
    float* out = (float*)d_out;
    float* rank_ws = (float*)d_ws;   // 2 * 1024 * 1024 floats = 8 MB

    rank_one_kernel<<<2 * B, NT, 0, stream>>>(s_v, s_l, pos_mask, neg_mask, rank_ws);
    combine_kernel<<<(B * B) / (NT * 4), NT, 0, stream>>>(rank_ws, w_v, w_l, out);
}

// Round 16
// 58.445 us; speedup vs baseline: 2.0769x; 1.3148x over previous
//
#include <hip/hip_runtime.h>
#include <hip/hip_fp16.h>

// DifferentiableRankIntegration, B=1024, tau=0.1, K=60.
// R16 = R15 with O(log NB) bucket ranking: 5 bit-ballots + mask intersection
// (NB=30<32; cat0 keyed to 31) replaces the 30-iteration ballot loop, and a
// precomputed segPre[k][unit] table replaces the per-item serial unit-prefix.
// Slot assignment is bit-identical to R15 -> numerics unchanged.
// Algorithm: value-bucket compaction, en = e^{u-c_bkt} (cat in mantissa LSBs);
// in-band (ib-1..ib+1): exact weighted quartic rational (1 rcp / 4 a-terms,
// numerators via synthetic division); out-of-band: 3-term sigma tails via
// geometric prefix/suffix tables (kappa^1,2,3). Pool ~17.8KB -> 8 blocks/CU.

constexpr int B = 1024;
constexpr int NT = 256;
constexpr int NB = 30;
constexpr int SLOTCAP = 1120;      // 1024 + 3*NB pads, rounded to 16
constexpr int QCAP = SLOTCAP / 4;  // 280
constexpr float L2E = 1.4426950408889634f;

constexpr int OFF_EN  = 0;                        // 4480 B
constexpr int OFF_CQ  = OFF_EN + SLOTCAP * 4;     // 8960 B (phase>=5: RankA/P)
constexpr int OFF_SEG = OFF_CQ + 4 * QCAP * 8;    // segCnt ushort[NB][16] = 960 B
constexpr int OFF_PRE = OFF_SEG + NB * 16 * 2;    // segPre ushort[NB][16] = 960 B
constexpr int OFF_TAB = OFF_PRE + NB * 16 * 2;    // Tab 14 rows x 36 cols = 2016 B
constexpr int OFF_BKQ = OFF_TAB + 14 * 36 * 4;    // BktQ QCAP = 280 B
constexpr int OFF_SST = OFF_BKQ + QCAP;           // segStart (NB+1)*4 = 124 B
constexpr int OFF_RED = OFF_SST + (NB + 1) * 4;   // Red 32 B
constexpr int POOL_BYTES = OFF_RED + 32;          // 17812 B

__global__ __launch_bounds__(NT, 8)
void rank_one_kernel(const float* __restrict__ s_v, const float* __restrict__ s_l,
                     const int* __restrict__ pos_m, const int* __restrict__ neg_m,
                     float* __restrict__ rank_ws) {
    __shared__ __align__(16) char pool[POOL_BYTES];
    float* En          = (float*)(pool + OFF_EN);
    float2* Ce12       = (float2*)(pool + OFF_CQ);
    float2* Ce34       = Ce12 + QCAP;
    uint2* ChA         = (uint2*)(Ce34 + QCAP);
    uint2* ChP         = ChA + QCAP;
    unsigned short (*segCnt)[16] = (unsigned short(*)[16])(pool + OFF_SEG);
    unsigned short (*segPre)[16] = (unsigned short(*)[16])(pool + OFF_PRE);
    float* TabF        = (float*)(pool + OFF_TAB);   // [cls*7+row][36]
    unsigned char* BktQ = (unsigned char*)(pool + OFF_BKQ);
    int* segStart      = (int*)(pool + OFF_SST);
    float* Red         = (float*)(pool + OFF_RED);
    float* RankA       = (float*)(pool + OFF_CQ);    // phase>=5 overlay
    float* RankP       = RankA + SLOTCAP;

    const int m = blockIdx.x >> 10;
    const int r = blockIdx.x & 1023;
    const float* __restrict__ S = m ? s_l : s_v;
    const int tid = threadIdx.x;
    const int lane = tid & 63;
    const int wvid = tid >> 6;
    const unsigned long long lmask = (1ull << lane) - 1ull;

    for (int s = tid; s < SLOTCAP; s += NT) En[s] = 0.f;  // pads: cat bits 0
    for (int j = tid; j < NB * 16 / 2; j += NT) ((int*)segCnt)[j] = 0;
    __syncthreads();

    // ---- Phase 1: read, u = s/tau, cat, row min/max ----
    float uu[4]; int cat[4];
    float mn = 1e30f, mx = -1e30f;
#pragma unroll
    for (int i = 0; i < 4; ++i) {
        const int c = tid + i * NT;
        uu[i] = S[r * B + c] * 10.0f;
        const int pf = pos_m[r * B + c] != 0, nf = neg_m[r * B + c] != 0;
        cat[i] = pf | (nf << 1);
        mn = fminf(mn, uu[i]); mx = fmaxf(mx, uu[i]);
    }
#pragma unroll
    for (int off = 1; off < 64; off <<= 1) {
        mn = fminf(mn, __shfl_xor(mn, off));
        mx = fmaxf(mx, __shfl_xor(mx, off));
    }
    if (lane == 0) { Red[wvid] = mn; Red[4 + wvid] = mx; }
    __syncthreads();

    const float lo = fminf(fminf(Red[0], Red[1]), fminf(Red[2], Red[3]));
    const float hi = fmaxf(fmaxf(Red[4], Red[5]), fmaxf(Red[6], Red[7]));
    const float umin = lo;
    const float Wb   = fmaxf((hi - lo) * (1.0001f / NB), 2.2f);
    const float invW = 1.0f / Wb;
    const float kap1 = exp2f(-Wb * L2E);
    const float kap2 = kap1 * kap1;
    const float kap3 = kap2 * kap1;
    const float eWm  = exp2f(Wb * L2E);

    // ---- Phase 1b: bucket keys; rank via 5 bit-ballots (NB<32, cat0 -> 31) ----
    int key[4], rk[4];
#pragma unroll
    for (int i = 0; i < 4; ++i) {
        int b = (int)((uu[i] - umin) * invW);
        b = b > NB - 1 ? NB - 1 : b;
        const int kk = cat[i] ? b : 31;
        key[i] = b;
        unsigned long long same = ~0ull;
#pragma unroll
        for (int j = 0; j < 5; ++j) {
            const unsigned long long bb = __ballot((kk >> j) & 1);
            same &= ((kk >> j) & 1) ? bb : ~bb;
        }
        rk[i] = (int)__popcll(same & lmask);
        if (cat[i] && rk[i] == 0)
            segCnt[kk][i * 4 + wvid] = (unsigned short)__popcll(same);
    }
    __syncthreads();

    // ---- Phase 2a: padded lengths + parallel unit-prefix table ----
    if (tid < NB) {
        int t = 0;
#pragma unroll
        for (int u = 0; u < 16; ++u) t += (int)segCnt[tid][u];
        segStart[tid] = (t + 3) & ~3;
    }
    for (int j = tid; j < NB * 16; j += NT) {
        const int k = j >> 4, u = j & 15;
        int p = 0;
        for (int v = 0; v < u; ++v) p += (int)segCnt[k][v];
        segPre[k][u] = (unsigned short)p;
    }
    __syncthreads();
    if (tid == 0) {
        int run = 0;
        for (int k = 0; k < NB; ++k) { int t = segStart[k]; segStart[k] = run; run += t; }
        segStart[NB] = run;
    }
    __syncthreads();

    // ---- Phase 2b: placement; slot in registers; cat in En mantissa LSBs ----
    int slot[4];
#pragma unroll
    for (int i = 0; i < 4; ++i) {
        slot[i] = 0;
        if (cat[i]) {
            const int k = key[i];
            slot[i] = segStart[k] + (int)segPre[k][i * 4 + wvid] + rk[i];
            const float cb = umin + ((float)k + 0.5f) * Wb;
            const float env = exp2f((uu[i] - cb) * L2E);
            unsigned eb = __float_as_uint(env);
            eb = (eb & ~3u) | (unsigned)cat[i];
            En[slot[i]] = __uint_as_float(eb);
        }
    }
    __syncthreads();

    const int nS = segStart[NB];
    const int nQ = nS >> 2;

    // ---- Phase 3a: Tab boundary zeros + quad coefficients + BktQ ----
    if (tid < 14 * 6) {                   // cols {0,1,32,33,34,35} per row
        const int row = tid / 6, ci = tid % 6;
        TabF[row * 36 + (ci < 2 ? ci : ci + 30)] = 0.f;   // disjoint from 3b's 2..31
    }
    for (int q = tid; q < nQ; q += NT) {
        int bq = 0;
        for (int k = 1; k < NB; ++k) bq += (4 * q >= segStart[k]);
        BktQ[q] = (unsigned char)bq;
        const float4 e4v = *(const float4*)&En[4 * q];
        const float en[4] = {e4v.x, e4v.y, e4v.z, e4v.w};
        const int fl[4] = {(int)(__float_as_uint(e4v.x) & 3u),
                           (int)(__float_as_uint(e4v.y) & 3u),
                           (int)(__float_as_uint(e4v.z) & 3u),
                           (int)(__float_as_uint(e4v.w) & 3u)};
        const float s01 = en[0] + en[1], p01 = en[0] * en[1];
        const float s23 = en[2] + en[3], p23 = en[2] * en[3];
        const float e1 = s01 + s23;
        const float e2 = fmaf(s01, s23, p01 + p23);
        const float e3 = fmaf(s01, p23, s23 * p01);
        const float e4 = p01 * p23;
        float nA3 = 0.f, nA2 = 0.f, nA1 = 0.f, nA0 = 0.f;
        float nP3 = 0.f, nP2 = 0.f, nP1 = 0.f, nP0 = 0.f;
#pragma unroll
        for (int j = 0; j < 4; ++j) {
            const float b1 = e1 - en[j];
            const float b2 = fmaf(-en[j], b1, e2);
            const float b3 = fmaf(-en[j], b2, e3);
            const float nn = (float)(fl[j] >> 1) * en[j];
            const float pp = (float)(fl[j] & 1) * en[j];
            nA3 += nn; nA2 = fmaf(nn, b1, nA2); nA1 = fmaf(nn, b2, nA1); nA0 = fmaf(nn, b3, nA0);
            nP3 += pp; nP2 = fmaf(pp, b1, nP2); nP1 = fmaf(pp, b2, nP1); nP0 = fmaf(pp, b3, nP0);
        }
        Ce12[q] = make_float2(e1, e2);
        Ce34[q] = make_float2(e3, e4);
        __half2 hA0 = __floats2half2_rn(nA3, nA2);
        __half2 hA1 = __floats2half2_rn(nA1, nA0);
        __half2 hP0 = __floats2half2_rn(nP3, nP2);
        __half2 hP1 = __floats2half2_rn(nP1, nP0);
        ChA[q] = make_uint2(reinterpret_cast<unsigned&>(hA0), reinterpret_cast<unsigned&>(hA1));
        ChP[q] = make_uint2(reinterpret_cast<unsigned&>(hP0), reinterpret_cast<unsigned&>(hP1));
    }
    // ---- Phase 3b: per-bucket tail sums, 8 threads/bucket + shfl reduce ----
    if (tid < NB * 8) {
        const int k = tid >> 3, o = tid & 7;
        float g1a=0,g2a=0,g3a=0,h1a=0,h2a=0,h3a=0,s0a=0;
        float g1p=0,g2p=0,g3p=0,h1p=0,h2p=0,h3p=0,s0p=0;
        for (int s = segStart[k] + o; s < segStart[k + 1]; s += 8) {
            const float en = En[s];
            const int f = (int)(__float_as_uint(en) & 3u);
            if (!f) continue;
            const float en2 = en * en, en3 = en2 * en;
            const float ren = __builtin_amdgcn_rcpf(en);
            const float ren2 = ren * ren, ren3 = ren2 * ren;
            const float nf = (float)(f >> 1), pf = (float)(f & 1);
            g1a = fmaf(nf,en,g1a);  g2a = fmaf(nf,en2,g2a);  g3a = fmaf(nf,en3,g3a);
            h1a = fmaf(nf,ren,h1a); h2a = fmaf(nf,ren2,h2a); h3a = fmaf(nf,ren3,h3a); s0a += nf;
            g1p = fmaf(pf,en,g1p);  g2p = fmaf(pf,en2,g2p);  g3p = fmaf(pf,en3,g3p);
            h1p = fmaf(pf,ren,h1p); h2p = fmaf(pf,ren2,h2p); h3p = fmaf(pf,ren3,h3p); s0p += pf;
        }
#define RED8(v) v += __shfl_xor(v, 4); v += __shfl_xor(v, 2); v += __shfl_xor(v, 1)
        RED8(g1a); RED8(g2a); RED8(g3a); RED8(h1a); RED8(h2a); RED8(h3a); RED8(s0a);
        RED8(g1p); RED8(g2p); RED8(g3p); RED8(h1p); RED8(h2p); RED8(h3p); RED8(s0p);
#undef RED8
        if (o == 0) {
            TabF[(0*7+0)*36+k+2]=g1a; TabF[(0*7+1)*36+k+2]=g2a; TabF[(0*7+2)*36+k+2]=g3a;
            TabF[(0*7+3)*36+k+2]=h1a; TabF[(0*7+4)*36+k+2]=h2a; TabF[(0*7+5)*36+k+2]=h3a;
            TabF[(0*7+6)*36+k+2]=s0a;
            TabF[(1*7+0)*36+k+2]=g1p; TabF[(1*7+1)*36+k+2]=g2p; TabF[(1*7+2)*36+k+2]=g3p;
            TabF[(1*7+3)*36+k+2]=h1p; TabF[(1*7+4)*36+k+2]=h2p; TabF[(1*7+5)*36+k+2]=h3p;
            TabF[(1*7+6)*36+k+2]=s0p;
        }
    }
    __syncthreads();
    // ---- Phase 3c: geometric prefix/suffix scans, 14-way parallel ----
    if (tid < 14) {
        const int row = tid % 7;
        float* Trow = &TabF[tid * 36];
        if (row < 3) {
            const float kp = row == 0 ? kap1 : (row == 1 ? kap2 : kap3);
            float r1 = 0.f;
            for (int k = 0; k < NB; ++k) { r1 = fmaf(r1, kp, Trow[k+2]); Trow[k+2] = r1; }
        } else if (row < 6) {
            const float kp = row == 3 ? kap1 : (row == 4 ? kap2 : kap3);
            float q1 = 0.f;
            for (int k = NB - 1; k >= 0; --k) { q1 = fmaf(q1, kp, Trow[k+2]); Trow[k+2] = q1; }
        } else {
            float s0 = 0.f;
            for (int k = NB - 1; k >= 0; --k) { s0 += Trow[k+2]; Trow[k+2] = s0; }
        }
    }
    __syncthreads();

    // ---- Phase 4: main — in-band quartic (3 fc-ranges) + 3-term tails ----
    float AN[4] = {0,0,0,0}, AP[4] = {0,0,0,0};
    const int s0i = 4 * tid;
    if (s0i < nS) {
        const float4 x4 = *(const float4*)&En[s0i];
        const float xb[4] = {x4.x, x4.y, x4.z, x4.w};
        const int ib = BktQ[tid];
        const int klo = ib > 0 ? ib - 1 : 0;
        const int khi = ib < NB - 1 ? ib + 1 : NB - 1;
        const int qs  = segStart[klo] >> 2;
        const int qe  = segStart[khi + 1] >> 2;
        const int qo0 = segStart[ib] >> 2;
        const int qo1 = segStart[ib + 1] >> 2;

        auto quadrun = [&](int q0, int q1, const float* xs) {
            for (int q = q0; q < q1; ++q) {
                const float2 e12 = Ce12[q], e34 = Ce34[q];
                const uint2 ha = ChA[q], hp = ChP[q];
                const float2 a01 = __half22float2(*(const __half2*)&ha.x);
                const float2 a23 = __half22float2(*(const __half2*)&ha.y);
                const float2 p01 = __half22float2(*(const __half2*)&hp.x);
                const float2 p23 = __half22float2(*(const __half2*)&hp.y);
#pragma unroll
                for (int i = 0; i < 4; ++i) {
                    const float x = xs[i];
                    float t = x + e12.x; t = fmaf(t, x, e12.y); t = fmaf(t, x, e34.x);
                    const float D = fmaf(t, x, e34.y);
                    float u = fmaf(a01.x, x, a01.y); u = fmaf(u, x, a23.x);
                    const float NA = fmaf(u, x, a23.y);
                    float v = fmaf(p01.x, x, p01.y); v = fmaf(v, x, p23.x);
                    const float NP = fmaf(v, x, p23.y);
                    const float rd = __builtin_amdgcn_rcpf(D);
                    AN[i] = fmaf(NA, rd, AN[i]);
                    AP[i] = fmaf(NP, rd, AP[i]);
                }
            }
        };
        float xsl[4], xsh[4];
#pragma unroll
        for (int i = 0; i < 4; ++i) { xsl[i] = xb[i] * eWm; xsh[i] = xb[i] * kap1; }
        quadrun(qs,  qo0, xsl);   // below-band buckets: fc = e^W
        quadrun(qo0, qo1, xb);    // own bucket: fc = 1
        quadrun(qo1, qe,  xsh);   // above-band buckets: fc = kappa

        // 3-term out-of-band tails (table reads hoisted; ib uniform per thread)
        const float P1a = TabF[(0*7+0)*36+ib],   P2a = TabF[(0*7+1)*36+ib],   P3a = TabF[(0*7+2)*36+ib];
        const float S1a = TabF[(0*7+3)*36+ib+4], S2a = TabF[(0*7+4)*36+ib+4], S3a = TabF[(0*7+5)*36+ib+4];
        const float S0a = TabF[(0*7+6)*36+ib+4];
        const float P1p = TabF[(1*7+0)*36+ib],   P2p = TabF[(1*7+1)*36+ib],   P3p = TabF[(1*7+2)*36+ib];
        const float S1p = TabF[(1*7+3)*36+ib+4], S2p = TabF[(1*7+4)*36+ib+4], S3p = TabF[(1*7+5)*36+ib+4];
        const float S0p = TabF[(1*7+6)*36+ib+4];
#pragma unroll
        for (int i = 0; i < 4; ++i) {
            const float eb = xb[i];
            const float rb = __builtin_amdgcn_rcpf(eb);
            const float tq = rb * kap2, sq = eb * kap2;
            const float tq2 = tq * tq, tq3 = tq2 * tq;
            const float sq2 = sq * sq, sq3 = sq2 * sq;
            AN[i] += tq * P1a - tq2 * P2a + tq3 * P3a
                   + S0a - sq * S1a + sq2 * S2a - sq3 * S3a;
            AP[i] += tq * P1p - tq2 * P2p + tq3 * P3p
                   + S0p - sq * S1p + sq2 * S2p - sq3 * S3p;
        }
    }
    __syncthreads();   // Cq dead -> overlay RankA/RankP

    // ---- Phase 5: write ranks BY SLOT (consecutive) ----
#pragma unroll
    for (int i = 0; i < 4; ++i) {
        RankA[s0i + i] = AN[i];
        RankP[s0i + i] = AP[i];
    }
    __syncthreads();

    // ---- Phase 6: gather via register slot[], write rank_m ----
#pragma unroll
    for (int i = 0; i < 4; ++i) {
        const int c = tid + i * NT;
        const bool pf = (cat[i] & 1) != 0;
        const bool nf = (cat[i] & 2) != 0;
        const float rk_ = (pf ? 1.f + RankA[slot[i]] : 0.f) +
                          (nf ? 1.f + RankP[slot[i]] : 0.f);
        rank_ws[m * (B * B) + r * B + c] = rk_;
    }
}

__global__ __launch_bounds__(NT, 8)
void combine_kernel(const float* __restrict__ rank_ws,
                    const float* __restrict__ w_v, const float* __restrict__ w_l,
                    float* __restrict__ out) {
    const int i4 = (blockIdx.x * NT + threadIdx.x) * 4;
    const float4 rv = *(const float4*)&rank_ws[i4];
    const float4 rl = *(const float4*)&rank_ws[B * B + i4];
    const float4 wv = *(const float4*)&w_v[i4];
    const float4 wl = *(const float4*)&w_l[i4];
    float4 o;
    o.x = 61.f * (wv.x / (60.f + rv.x) + wl.x / (60.f + rl.x));
    o.y = 61.f * (wv.y / (60.f + rv.y) + wl.y / (60.f + rl.y));
    o.z = 61.f * (wv.z / (60.f + rv.z) + wl.z / (60.f + rl.z));
    o.w = 61.f * (wv.w / (60.f + rv.w) + wl.w / (60.f + rl.w));
    *(float4*)&out[i4] = o;
}

extern "C" void kernel_launch(void* const* d_in, const int* in_sizes, int n_in,
                              void* d_out, int out_size, void* d_ws, size_t ws_size,
                              hipStream_t stream) {
    const float* s_v = (const float*)d_in[0];
    const float* s_l = (const float*)d_in[1];
    const int* pos_mask = (const int*)d_in[2];
    const int* neg_mask = (const int*)d_in[3];
    const float* w_v = (const float*)d_in[4];
    const float* w_l = (const float*)d_in[5];
    float* out = (float*)d_out;
    float* rank_ws = (float*)d_ws;   // 2 * 1024 * 1024 floats = 8 MB

    rank_one_kernel<<<2 * B, NT, 0, stream>>>(s_v, s_l, pos_mask, neg_mask, rank_ws);
    combine_kernel<<<(B * B) / (NT * 4), NT, 0, stream>>>(rank_ws, w_v, w_l, out);
}

// Round 17
// 51.351 us; speedup vs baseline: 2.3638x; 1.1382x over previous
//
#include <hip/hip_runtime.h>
#include <hip/hip_fp16.h>

// DifferentiableRankIntegration, B=1024, tau=0.1, K=60.
// R17 = R16 with NB=45 / W>=1.5 and 4-term tails: in-band (3-bucket) band
// narrows 6.6 -> ~4.5 u-units (x0.68 on the dominant quartic stream); tail
// series gets a 4th term to hold accuracy. segCnt -> uchar and Tab 18x51 to
// keep pool = 20356B <= 20480 (8 blocks/CU).
// Algorithm: value-bucket compaction, en = e^{u-c_bkt} (cat in mantissa LSBs);
// in-band (ib-1..ib+1): exact weighted quartic rational (1 rcp / 4 a-terms,
// numerators via synthetic division, fp16-packed); out-of-band: 4-term sigma
// tails via geometric prefix/suffix tables (kappa^1..4 recurrences).

constexpr int B = 1024;
constexpr int NT = 256;
constexpr int NB = 45;
constexpr int SLOTCAP = 1168;      // 1024 + up to 135 pads, rounded to 16
constexpr int QCAP = SLOTCAP / 4;  // 292
constexpr float L2E = 1.4426950408889634f;
constexpr int TCOLS = NB + 6;      // 51

constexpr int OFF_EN  = 0;                        // 4672 B
constexpr int OFF_CQ  = OFF_EN + SLOTCAP * 4;     // 9344 B (phase>=5: RankA/P)
constexpr int OFF_SEG = OFF_CQ + 4 * QCAP * 8;    // segCnt uchar[NB][16] = 720 B
constexpr int OFF_PRE = OFF_SEG + NB * 16;        // segPre ushort[NB][16] = 1440 B
constexpr int OFF_TAB = OFF_PRE + NB * 16 * 2;    // Tab 18 x 51 x 4 = 3672 B
constexpr int OFF_BKQ = OFF_TAB + 18 * TCOLS * 4; // BktQ QCAP = 292 B
constexpr int OFF_SST = OFF_BKQ + QCAP;           // segStart 46*4 = 184 B
constexpr int OFF_RED = OFF_SST + (NB + 1) * 4;   // Red 32 B
constexpr int POOL_BYTES = OFF_RED + 32;          // 20356 B <= 20480

__global__ __launch_bounds__(NT, 8)
void rank_one_kernel(const float* __restrict__ s_v, const float* __restrict__ s_l,
                     const int* __restrict__ pos_m, const int* __restrict__ neg_m,
                     float* __restrict__ rank_ws) {
    __shared__ __align__(16) char pool[POOL_BYTES];
    float* En          = (float*)(pool + OFF_EN);
    float2* Ce12       = (float2*)(pool + OFF_CQ);
    float2* Ce34       = Ce12 + QCAP;
    uint2* ChA         = (uint2*)(Ce34 + QCAP);
    uint2* ChP         = ChA + QCAP;
    unsigned char (*segCnt)[16]  = (unsigned char(*)[16])(pool + OFF_SEG);
    unsigned short (*segPre)[16] = (unsigned short(*)[16])(pool + OFF_PRE);
    float* TabF        = (float*)(pool + OFF_TAB);   // [(cls*9+row)*TCOLS + col]
    unsigned char* BktQ = (unsigned char*)(pool + OFF_BKQ);
    int* segStart      = (int*)(pool + OFF_SST);
    float* Red         = (float*)(pool + OFF_RED);
    float* RankA       = (float*)(pool + OFF_CQ);    // phase>=5 overlay
    float* RankP       = RankA + SLOTCAP;

    const int m = blockIdx.x >> 10;
    const int r = blockIdx.x & 1023;
    const float* __restrict__ S = m ? s_l : s_v;
    const int tid = threadIdx.x;
    const int lane = tid & 63;
    const int wvid = tid >> 6;
    const unsigned long long lmask = (1ull << lane) - 1ull;

    for (int s = tid; s < SLOTCAP; s += NT) En[s] = 0.f;  // pads: cat bits 0
    for (int j = tid; j < NB * 16 / 4; j += NT) ((int*)segCnt)[j] = 0;
    __syncthreads();

    // ---- Phase 1: read, u = s/tau, cat, row min/max ----
    float uu[4]; int cat[4];
    float mn = 1e30f, mx = -1e30f;
#pragma unroll
    for (int i = 0; i < 4; ++i) {
        const int c = tid + i * NT;
        uu[i] = S[r * B + c] * 10.0f;
        const int pf = pos_m[r * B + c] != 0, nf = neg_m[r * B + c] != 0;
        cat[i] = pf | (nf << 1);
        mn = fminf(mn, uu[i]); mx = fmaxf(mx, uu[i]);
    }
#pragma unroll
    for (int off = 1; off < 64; off <<= 1) {
        mn = fminf(mn, __shfl_xor(mn, off));
        mx = fmaxf(mx, __shfl_xor(mx, off));
    }
    if (lane == 0) { Red[wvid] = mn; Red[4 + wvid] = mx; }
    __syncthreads();

    const float lo = fminf(fminf(Red[0], Red[1]), fminf(Red[2], Red[3]));
    const float hi = fmaxf(fmaxf(Red[4], Red[5]), fmaxf(Red[6], Red[7]));
    const float umin = lo;
    const float Wb   = fmaxf((hi - lo) * (1.0001f / NB), 1.5f);
    const float invW = 1.0f / Wb;
    const float kap1 = exp2f(-Wb * L2E);
    const float kap2 = kap1 * kap1;
    const float kap3 = kap2 * kap1;
    const float kap4 = kap2 * kap2;
    const float eWm  = exp2f(Wb * L2E);

    // ---- Phase 1b: bucket keys; rank via 6 bit-ballots (NB<64, cat0 -> 63) ----
    int key[4], rk[4];
#pragma unroll
    for (int i = 0; i < 4; ++i) {
        int b = (int)((uu[i] - umin) * invW);
        b = b > NB - 1 ? NB - 1 : b;
        const int kk = cat[i] ? b : 63;
        key[i] = b;
        unsigned long long same = ~0ull;
#pragma unroll
        for (int j = 0; j < 6; ++j) {
            const unsigned long long bb = __ballot((kk >> j) & 1);
            same &= ((kk >> j) & 1) ? bb : ~bb;
        }
        rk[i] = (int)__popcll(same & lmask);
        if (cat[i] && rk[i] == 0)
            segCnt[kk][i * 4 + wvid] = (unsigned char)__popcll(same);
    }
    __syncthreads();

    // ---- Phase 2a: padded lengths + parallel unit-prefix table ----
    if (tid < NB) {
        int t = 0;
#pragma unroll
        for (int u = 0; u < 16; ++u) t += (int)segCnt[tid][u];
        segStart[tid] = (t + 3) & ~3;
    }
    for (int j = tid; j < NB * 16; j += NT) {
        const int k = j >> 4, u = j & 15;
        int p = 0;
        for (int v = 0; v < u; ++v) p += (int)segCnt[k][v];
        segPre[k][u] = (unsigned short)p;
    }
    __syncthreads();
    if (tid == 0) {
        int run = 0;
        for (int k = 0; k < NB; ++k) { int t = segStart[k]; segStart[k] = run; run += t; }
        segStart[NB] = run;
    }
    __syncthreads();

    // ---- Phase 2b: placement; slot in registers; cat in En mantissa LSBs ----
    int slot[4];
#pragma unroll
    for (int i = 0; i < 4; ++i) {
        slot[i] = 0;
        if (cat[i]) {
            const int k = key[i];
            slot[i] = segStart[k] + (int)segPre[k][i * 4 + wvid] + rk[i];
            const float cb = umin + ((float)k + 0.5f) * Wb;
            const float env = exp2f((uu[i] - cb) * L2E);
            unsigned eb = __float_as_uint(env);
            eb = (eb & ~3u) | (unsigned)cat[i];
            En[slot[i]] = __uint_as_float(eb);
        }
    }
    __syncthreads();

    const int nS = segStart[NB];
    const int nQ = nS >> 2;

    // ---- Phase 3a: Tab boundary zeros + quad coefficients + BktQ ----
    if (tid < 18 * 6) {                   // cols {0,1,47,48,49,50} per row
        const int row = tid / 6, ci = tid % 6;
        TabF[row * TCOLS + (ci < 2 ? ci : ci + 45)] = 0.f;  // disjoint from 3b's 2..46
    }
    for (int q = tid; q < nQ; q += NT) {
        int bq = 0;
        for (int k = 1; k < NB; ++k) bq += (4 * q >= segStart[k]);
        BktQ[q] = (unsigned char)bq;
        const float4 e4v = *(const float4*)&En[4 * q];
        const float en[4] = {e4v.x, e4v.y, e4v.z, e4v.w};
        const int fl[4] = {(int)(__float_as_uint(e4v.x) & 3u),
                           (int)(__float_as_uint(e4v.y) & 3u),
                           (int)(__float_as_uint(e4v.z) & 3u),
                           (int)(__float_as_uint(e4v.w) & 3u)};
        const float s01 = en[0] + en[1], p01 = en[0] * en[1];
        const float s23 = en[2] + en[3], p23 = en[2] * en[3];
        const float e1 = s01 + s23;
        const float e2 = fmaf(s01, s23, p01 + p23);
        const float e3 = fmaf(s01, p23, s23 * p01);
        const float e4 = p01 * p23;
        float nA3 = 0.f, nA2 = 0.f, nA1 = 0.f, nA0 = 0.f;
        float nP3 = 0.f, nP2 = 0.f, nP1 = 0.f, nP0 = 0.f;
#pragma unroll
        for (int j = 0; j < 4; ++j) {
            const float b1 = e1 - en[j];
            const float b2 = fmaf(-en[j], b1, e2);
            const float b3 = fmaf(-en[j], b2, e3);
            const float nn = (float)(fl[j] >> 1) * en[j];
            const float pp = (float)(fl[j] & 1) * en[j];
            nA3 += nn; nA2 = fmaf(nn, b1, nA2); nA1 = fmaf(nn, b2, nA1); nA0 = fmaf(nn, b3, nA0);
            nP3 += pp; nP2 = fmaf(pp, b1, nP2); nP1 = fmaf(pp, b2, nP1); nP0 = fmaf(pp, b3, nP0);
        }
        Ce12[q] = make_float2(e1, e2);
        Ce34[q] = make_float2(e3, e4);
        __half2 hA0 = __floats2half2_rn(nA3, nA2);
        __half2 hA1 = __floats2half2_rn(nA1, nA0);
        __half2 hP0 = __floats2half2_rn(nP3, nP2);
        __half2 hP1 = __floats2half2_rn(nP1, nP0);
        ChA[q] = make_uint2(reinterpret_cast<unsigned&>(hA0), reinterpret_cast<unsigned&>(hA1));
        ChP[q] = make_uint2(reinterpret_cast<unsigned&>(hP0), reinterpret_cast<unsigned&>(hP1));
    }
    // ---- Phase 3b: per-bucket tail sums, 4 threads/bucket + shfl reduce ----
    if (tid < NB * 4) {
        const int k = tid >> 2, o = tid & 3;
        float g1a=0,g2a=0,g3a=0,g4a=0,h1a=0,h2a=0,h3a=0,h4a=0,s0a=0;
        float g1p=0,g2p=0,g3p=0,g4p=0,h1p=0,h2p=0,h3p=0,h4p=0,s0p=0;
        for (int s = segStart[k] + o; s < segStart[k + 1]; s += 4) {
            const float en = En[s];
            const int f = (int)(__float_as_uint(en) & 3u);
            if (!f) continue;
            const float en2 = en * en, en3 = en2 * en, en4 = en2 * en2;
            const float ren = __builtin_amdgcn_rcpf(en);
            const float ren2 = ren * ren, ren3 = ren2 * ren, ren4 = ren2 * ren2;
            const float nf = (float)(f >> 1), pf = (float)(f & 1);
            g1a = fmaf(nf,en,g1a);  g2a = fmaf(nf,en2,g2a);  g3a = fmaf(nf,en3,g3a);  g4a = fmaf(nf,en4,g4a);
            h1a = fmaf(nf,ren,h1a); h2a = fmaf(nf,ren2,h2a); h3a = fmaf(nf,ren3,h3a); h4a = fmaf(nf,ren4,h4a); s0a += nf;
            g1p = fmaf(pf,en,g1p);  g2p = fmaf(pf,en2,g2p);  g3p = fmaf(pf,en3,g3p);  g4p = fmaf(pf,en4,g4p);
            h1p = fmaf(pf,ren,h1p); h2p = fmaf(pf,ren2,h2p); h3p = fmaf(pf,ren3,h3p); h4p = fmaf(pf,ren4,h4p); s0p += pf;
        }
#define RED4(v) v += __shfl_xor(v, 2); v += __shfl_xor(v, 1)
        RED4(g1a); RED4(g2a); RED4(g3a); RED4(g4a); RED4(h1a); RED4(h2a); RED4(h3a); RED4(h4a); RED4(s0a);
        RED4(g1p); RED4(g2p); RED4(g3p); RED4(g4p); RED4(h1p); RED4(h2p); RED4(h3p); RED4(h4p); RED4(s0p);
#undef RED4
        if (o == 0) {
            TabF[(0*9+0)*TCOLS+k+2]=g1a; TabF[(0*9+1)*TCOLS+k+2]=g2a; TabF[(0*9+2)*TCOLS+k+2]=g3a; TabF[(0*9+3)*TCOLS+k+2]=g4a;
            TabF[(0*9+4)*TCOLS+k+2]=h1a; TabF[(0*9+5)*TCOLS+k+2]=h2a; TabF[(0*9+6)*TCOLS+k+2]=h3a; TabF[(0*9+7)*TCOLS+k+2]=h4a;
            TabF[(0*9+8)*TCOLS+k+2]=s0a;
            TabF[(1*9+0)*TCOLS+k+2]=g1p; TabF[(1*9+1)*TCOLS+k+2]=g2p; TabF[(1*9+2)*TCOLS+k+2]=g3p; TabF[(1*9+3)*TCOLS+k+2]=g4p;
            TabF[(1*9+4)*TCOLS+k+2]=h1p; TabF[(1*9+5)*TCOLS+k+2]=h2p; TabF[(1*9+6)*TCOLS+k+2]=h3p; TabF[(1*9+7)*TCOLS+k+2]=h4p;
            TabF[(1*9+8)*TCOLS+k+2]=s0p;
        }
    }
    __syncthreads();
    // ---- Phase 3c: geometric prefix/suffix scans, 18-way parallel ----
    if (tid < 18) {
        const int row = tid % 9;
        float* Trow = &TabF[tid * TCOLS];
        if (row < 4) {
            const float kp = row == 0 ? kap1 : (row == 1 ? kap2 : (row == 2 ? kap3 : kap4));
            float r1 = 0.f;
            for (int k = 0; k < NB; ++k) { r1 = fmaf(r1, kp, Trow[k+2]); Trow[k+2] = r1; }
        } else if (row < 8) {
            const float kp = row == 4 ? kap1 : (row == 5 ? kap2 : (row == 6 ? kap3 : kap4));
            float q1 = 0.f;
            for (int k = NB - 1; k >= 0; --k) { q1 = fmaf(q1, kp, Trow[k+2]); Trow[k+2] = q1; }
        } else {
            float s0 = 0.f;
            for (int k = NB - 1; k >= 0; --k) { s0 += Trow[k+2]; Trow[k+2] = s0; }
        }
    }
    __syncthreads();

    // ---- Phase 4: main — in-band quartic (3 fc-ranges) + 4-term tails ----
    float AN[4] = {0,0,0,0}, AP[4] = {0,0,0,0};
    const int s0i = 4 * tid;
    if (s0i < nS) {
        const float4 x4 = *(const float4*)&En[s0i];
        const float xb[4] = {x4.x, x4.y, x4.z, x4.w};
        const int ib = BktQ[tid];
        const int klo = ib > 0 ? ib - 1 : 0;
        const int khi = ib < NB - 1 ? ib + 1 : NB - 1;
        const int qs  = segStart[klo] >> 2;
        const int qe  = segStart[khi + 1] >> 2;
        const int qo0 = segStart[ib] >> 2;
        const int qo1 = segStart[ib + 1] >> 2;

        auto quadrun = [&](int q0, int q1, const float* xs) {
            for (int q = q0; q < q1; ++q) {
                const float2 e12 = Ce12[q], e34 = Ce34[q];
                const uint2 ha = ChA[q], hp = ChP[q];
                const float2 a01 = __half22float2(*(const __half2*)&ha.x);
                const float2 a23 = __half22float2(*(const __half2*)&ha.y);
                const float2 p01 = __half22float2(*(const __half2*)&hp.x);
                const float2 p23 = __half22float2(*(const __half2*)&hp.y);
#pragma unroll
                for (int i = 0; i < 4; ++i) {
                    const float x = xs[i];
                    float t = x + e12.x; t = fmaf(t, x, e12.y); t = fmaf(t, x, e34.x);
                    const float D = fmaf(t, x, e34.y);
                    float u = fmaf(a01.x, x, a01.y); u = fmaf(u, x, a23.x);
                    const float NA = fmaf(u, x, a23.y);
                    float v = fmaf(p01.x, x, p01.y); v = fmaf(v, x, p23.x);
                    const float NP = fmaf(v, x, p23.y);
                    const float rd = __builtin_amdgcn_rcpf(D);
                    AN[i] = fmaf(NA, rd, AN[i]);
                    AP[i] = fmaf(NP, rd, AP[i]);
                }
            }
        };
        float xsl[4], xsh[4];
#pragma unroll
        for (int i = 0; i < 4; ++i) { xsl[i] = xb[i] * eWm; xsh[i] = xb[i] * kap1; }
        quadrun(qs,  qo0, xsl);   // below-band buckets: fc = e^W
        quadrun(qo0, qo1, xb);    // own bucket: fc = 1
        quadrun(qo1, qe,  xsh);   // above-band buckets: fc = kappa

        // 4-term out-of-band tails (table reads hoisted; ib uniform per thread)
        const float P1a = TabF[(0*9+0)*TCOLS+ib],   P2a = TabF[(0*9+1)*TCOLS+ib];
        const float P3a = TabF[(0*9+2)*TCOLS+ib],   P4a = TabF[(0*9+3)*TCOLS+ib];
        const float S1a = TabF[(0*9+4)*TCOLS+ib+4], S2a = TabF[(0*9+5)*TCOLS+ib+4];
        const float S3a = TabF[(0*9+6)*TCOLS+ib+4], S4a = TabF[(0*9+7)*TCOLS+ib+4];
        const float S0a = TabF[(0*9+8)*TCOLS+ib+4];
        const float P1p = TabF[(1*9+0)*TCOLS+ib],   P2p = TabF[(1*9+1)*TCOLS+ib];
        const float P3p = TabF[(1*9+2)*TCOLS+ib],   P4p = TabF[(1*9+3)*TCOLS+ib];
        const float S1p = TabF[(1*9+4)*TCOLS+ib+4], S2p = TabF[(1*9+5)*TCOLS+ib+4];
        const float S3p = TabF[(1*9+6)*TCOLS+ib+4], S4p = TabF[(1*9+7)*TCOLS+ib+4];
        const float S0p = TabF[(1*9+8)*TCOLS+ib+4];
#pragma unroll
        for (int i = 0; i < 4; ++i) {
            const float eb = xb[i];
            const float rb = __builtin_amdgcn_rcpf(eb);
            const float tq = rb * kap2, sq = eb * kap2;
            const float tq2 = tq * tq, tq3 = tq2 * tq, tq4 = tq2 * tq2;
            const float sq2 = sq * sq, sq3 = sq2 * sq, sq4 = sq2 * sq2;
            AN[i] += tq * P1a - tq2 * P2a + tq3 * P3a - tq4 * P4a
                   + S0a - sq * S1a + sq2 * S2a - sq3 * S3a + sq4 * S4a;
            AP[i] += tq * P1p - tq2 * P2p + tq3 * P3p - tq4 * P4p
                   + S0p - sq * S1p + sq2 * S2p - sq3 * S3p + sq4 * S4p;
        }
    }
    __syncthreads();   // Cq dead -> overlay RankA/RankP

    // ---- Phase 5: write ranks BY SLOT (consecutive) ----
#pragma unroll
    for (int i = 0; i < 4; ++i) {
        RankA[s0i + i] = AN[i];
        RankP[s0i + i] = AP[i];
    }
    __syncthreads();

    // ---- Phase 6: gather via register slot[], write rank_m ----
#pragma unroll
    for (int i = 0; i < 4; ++i) {
        const int c = tid + i * NT;
        const bool pf = (cat[i] & 1) != 0;
        const bool nf = (cat[i] & 2) != 0;
        const float rk_ = (pf ? 1.f + RankA[slot[i]] : 0.f) +
                          (nf ? 1.f + RankP[slot[i]] : 0.f);
        rank_ws[m * (B * B) + r * B + c] = rk_;
    }
}

__global__ __launch_bounds__(NT, 8)
void combine_kernel(const float* __restrict__ rank_ws,
                    const float* __restrict__ w_v, const float* __restrict__ w_l,
                    float* __restrict__ out) {
    const int i4 = (blockIdx.x * NT + threadIdx.x) * 4;
    const float4 rv = *(const float4*)&rank_ws[i4];
    const float4 rl = *(const float4*)&rank_ws[B * B + i4];
    const float4 wv = *(const float4*)&w_v[i4];
    const float4 wl = *(const float4*)&w_l[i4];
    float4 o;
    o.x = 61.f * (wv.x / (60.f + rv.x) + wl.x / (60.f + rl.x));
    o.y = 61.f * (wv.y / (60.f + rv.y) + wl.y / (60.f + rl.y));
    o.z = 61.f * (wv.z / (60.f + rv.z) + wl.z / (60.f + rl.z));
    o.w = 61.f * (wv.w / (60.f + rv.w) + wl.w / (60.f + rl.w));
    *(float4*)&out[i4] = o;
}

extern "C" void kernel_launch(void* const* d_in, const int* in_sizes, int n_in,
                              void* d_out, int out_size, void* d_ws, size_t ws_size,
                              hipStream_t stream) {
    const float* s_v = (const float*)d_in[0];
    const float* s_l = (const float*)d_in[1];
    const int* pos_mask = (const int*)d_in[2];
    const int* neg_mask = (const int*)d_in[3];
    const float* w_v = (const float*)d_in[4];
    const float* w_l = (const float*)d_in[5];
    float* out = (float*)d_out;
    float* rank_ws = (float*)d_ws;   // 2 * 1024 * 1024 floats = 8 MB

    rank_one_kernel<<<2 * B, NT, 0, stream>>>(s_v, s_l, pos_mask, neg_mask, rank_ws);
    combine_kernel<<<(B * B) / (NT * 4), NT, 0, stream>>>(rank_ws, w_v, w_l, out);
}